// Round 4
// baseline (14244.218 us; speedup 1.0000x reference)
//
#include <hip/hip_runtime.h>
#include <stdint.h>

#define NCAND 100000
#define NB    1024
#define DNUM  96
#define DM    256
#define DH    512
#define MCTX  96
#define LNEPS 1e-5f

extern "C" __global__ __launch_bounds__(256)
void fill_out_k(float* out, int n)
{
    int i = blockIdx.x * 256 + threadIdx.x;
    if (i < n) out[i] = 777.0f;
}

// C[M,N] = A[M,K] @ B  (+bias, +resid, ReLU)  or sim-epilogue (2*acc - colb[n])
// btrans: B is [N,K] row-major (dot of rows) ; else B is [K,N] row-major.
extern "C" __global__ __launch_bounds__(256)
void gemm128(const float* A, const float* B, float* C,
             const float* bias, const float* resid, const float* colb,
             int M, int N, int K, int btrans, int dorelu, int simepi)
{
    __shared__ float As[16][130];
    __shared__ float Bs[16][130];
    int t = threadIdx.x;
    int tx = t & 15, ty = t >> 4;
    int m0 = blockIdx.y * 128;
    int n0 = blockIdx.x * 128;
    float acc[8][8];
    int i, j, kk;
    for (i = 0; i < 8; i++) for (j = 0; j < 8; j++) acc[i][j] = 0.0f;
    int am  = t >> 1;        // A row within tile (0..127)
    int ak  = (t & 1) * 8;   // A k-offset (0 or 8)
    int bk  = t >> 4;        // B k (0..15)        for !btrans
    int bn  = (t & 15) * 8;  // B col base         for !btrans
    int bn2 = t >> 1;        // B col (0..127)     for btrans
    int bk2 = (t & 1) * 8;   // B k-offset         for btrans

    for (int k0 = 0; k0 < K; k0 += 16) {   // K is always a multiple of 16 here
        float av[8], bv[8];
        int arow = m0 + am;
        for (i = 0; i < 8; i++)
            av[i] = (arow < M) ? A[(long long)arow * K + (k0 + ak + i)] : 0.0f;
        if (btrans) {
            int col = n0 + bn2;
            for (i = 0; i < 8; i++)
                bv[i] = (col < N) ? B[(long long)col * K + (k0 + bk2 + i)] : 0.0f;
        } else {
            int col = n0 + bn;
            for (i = 0; i < 8; i++)
                bv[i] = (col + i < N) ? B[(long long)(k0 + bk) * N + (col + i)] : 0.0f;
        }
        __syncthreads();     // protect previous iteration's LDS reads
        for (i = 0; i < 8; i++) As[ak + i][am] = av[i];
        if (btrans) { for (i = 0; i < 8; i++) Bs[bk2 + i][bn2] = bv[i]; }
        else        { for (i = 0; i < 8; i++) Bs[bk][bn + i] = bv[i]; }
        __syncthreads();
        for (kk = 0; kk < 16; kk++) {
            float a[8], b[8];
            for (i = 0; i < 4; i++) { a[i] = As[kk][ty * 4 + i]; a[i + 4] = As[kk][64 + ty * 4 + i]; }
            for (j = 0; j < 4; j++) { b[j] = Bs[kk][tx * 4 + j]; b[j + 4] = Bs[kk][64 + tx * 4 + j]; }
            for (i = 0; i < 8; i++)
                for (j = 0; j < 8; j++) acc[i][j] = fmaf(a[i], b[j], acc[i][j]);
        }
    }
    for (i = 0; i < 8; i++) {
        int row = m0 + ((i < 4) ? (ty * 4 + i) : (64 + ty * 4 + (i - 4)));
        if (row >= M) continue;
        for (j = 0; j < 8; j++) {
            int col = n0 + ((j < 4) ? (tx * 4 + j) : (64 + tx * 4 + (j - 4)));
            if (col >= N) continue;
            float v = acc[i][j];
            if (simepi) {
                v = 2.0f * v - colb[col];
            } else {
                if (bias)  v += bias[col];
                if (resid) v += resid[(long long)row * N + col];
                if (dorelu && v < 0.0f) v = 0.0f;
            }
            C[(long long)row * N + col] = v;
        }
    }
}

extern "C" __global__ __launch_bounds__(256)
void ln256(const float* X, float* Y, const float* g, const float* b)
{
    __shared__ float sred[256];
    int r = blockIdx.x, t = threadIdx.x;
    float x = X[(long long)r * DM + t];
    sred[t] = x; __syncthreads();
    for (int s = 128; s > 0; s >>= 1) { if (t < s) sred[t] += sred[t + s]; __syncthreads(); }
    float mu = sred[0] * (1.0f / DM); __syncthreads();
    float d = x - mu;
    sred[t] = d * d; __syncthreads();
    for (int s = 128; s > 0; s >>= 1) { if (t < s) sred[t] += sred[t + s]; __syncthreads(); }
    float var = sred[0] * (1.0f / DM);
    Y[(long long)r * DM + t] = d * rsqrtf(var + LNEPS) * g[t] + b[t];
}

extern "C" __global__ __launch_bounds__(256)
void snorm_k(const float* Kc, float* sc)
{
    __shared__ float sred[256];
    int c = blockIdx.x, t = threadIdx.x;
    float v = Kc[(long long)c * DM + t];
    sred[t] = v * v; __syncthreads();
    for (int s = 128; s > 0; s >>= 1) { if (t < s) sred[t] += sred[t + s]; __syncthreads(); }
    if (t == 0) sc[c] = sred[0];
}

__device__ unsigned fmapf(float f)
{
    unsigned u = __float_as_uint(f);
    return u ^ (unsigned)(((int)u >> 31) | (int)0x80000000);
}

// exact top-96 per query row (radix select over 4x8-bit), ties -> smallest index,
// then softmax probabilities. Order of (idx,p) pairs is arbitrary: downstream
// use is permutation-invariant weighted sums.
extern "C" __global__ __launch_bounds__(256)
void topk_k(const float* S, int q0, int* out_idx, float* out_p)
{
    int t = threadIdx.x;
    const float* row = S + (long long)blockIdx.x * NCAND;
    __shared__ int hist8[8][256];
    __shared__ unsigned sh_prefix;
    __shared__ int sh_want, cntG, cntE;
    __shared__ int   gidx[128];
    __shared__ float gval[128];
    __shared__ int   eqi[2048];
    __shared__ float vals[MCTX];
    __shared__ int   inds[MCTX];
    __shared__ float pr[MCTX];

    if (t == 0) { sh_prefix = 0u; sh_want = MCTX; cntG = 0; cntE = 0; }

    for (int lvl = 0; lvl < 4; lvl++) {
        int shift = 24 - 8 * lvl;
        for (int i = t; i < 2048; i += 256) ((int*)hist8)[i] = 0;
        __syncthreads();
        unsigned prefix = sh_prefix;
        unsigned mask = (lvl == 0) ? 0u : (0xFFFFFFFFu << (shift + 8));
        int* hrow = hist8[t & 7];
        for (int c = t; c < NCAND; c += 256) {
            unsigned key = fmapf(row[c]);
            if ((key & mask) == prefix) atomicAdd(&hrow[(key >> shift) & 255], 1);
        }
        __syncthreads();
        {
            int s = 0;
            for (int g2 = 1; g2 < 8; g2++) s += hist8[g2][t];
            hist8[0][t] += s;
        }
        __syncthreads();
        if (t == 0) {
            int want = sh_want, cum = 0;
            for (int b2 = 255; b2 >= 0; b2--) {
                cum += hist8[0][b2];
                if (cum >= want) {
                    sh_want = want - (cum - hist8[0][b2]);
                    sh_prefix = prefix | ((unsigned)b2 << shift);
                    break;
                }
            }
        }
        __syncthreads();
    }
    unsigned T = sh_prefix;
    for (int c = t; c < NCAND; c += 256) {
        unsigned key = fmapf(row[c]);
        if (key > T) {
            int p = atomicAdd(&cntG, 1);
            if (p < 128) { gidx[p] = c; gval[p] = row[c]; }
        } else if (key == T) {
            int p = atomicAdd(&cntE, 1);
            if (p < 2048) eqi[p] = c;
        }
    }
    __syncthreads();
    if (t == 0) {
        int nG = cntG; if (nG > MCTX) nG = MCTX;
        int nE = cntE; if (nE > 2048) nE = 2048;
        int need = MCTX - nG;
        for (int i = 0; i < nG; i++) { inds[i] = gidx[i]; vals[i] = gval[i]; }
        for (int s = 0; s < need; s++) {
            int best = 0x7FFFFFFF, bp = -1;
            for (int e = 0; e < nE; e++) if (eqi[e] < best) { best = eqi[e]; bp = e; }
            if (bp >= 0) { eqi[bp] = 0x7FFFFFFF; inds[nG + s] = best; vals[nG + s] = row[best]; }
            else         { inds[nG + s] = 0;     vals[nG + s] = -3.0e38f; }
        }
        float mx = -3.4e38f;
        for (int i = 0; i < MCTX; i++) if (vals[i] > mx) mx = vals[i];
        float sum = 0.0f;
        for (int i = 0; i < MCTX; i++) { float e = expf(vals[i] - mx); pr[i] = e; sum += e; }
        float inv = 1.0f / sum;
        for (int i = 0; i < MCTX; i++) pr[i] *= inv;
    }
    __syncthreads();
    if (t < MCTX) {
        long long o = (long long)(q0 + blockIdx.x) * MCTX + t;
        out_idx[o] = inds[t];
        out_p[o]   = pr[t];
    }
}

extern "C" __global__ __launch_bounds__(256)
void gatherD_k(const float* kq, const float* Kc, const int* idx, float* D)
{
    int r = blockIdx.x, t = threadIdx.x;
    int b = r / MCTX;                    // local to chunk
    int ci = idx[r];
    D[(long long)r * DM + t] = kq[(long long)b * DM + t] - Kc[(long long)ci * DM + t];
}

extern "C" __global__ __launch_bounds__(256)
void ybar_k(const float* P, const int* idx, const float* y, float* ybar)
{
    __shared__ float sred[256];
    int b = blockIdx.x, t = threadIdx.x;
    float v = 0.0f;
    if (t < MCTX) v = P[(long long)b * MCTX + t] * y[idx[(long long)b * MCTX + t]];
    sred[t] = v; __syncthreads();
    for (int s = 128; s > 0; s >>= 1) { if (t < s) sred[t] += sred[t + s]; __syncthreads(); }
    if (t == 0) ybar[b] = sred[0];
}

extern "C" __global__ __launch_bounds__(512)
void wsum_k(const float* U, const float* P, float* u)
{
    __shared__ float pl[MCTX];
    int b = blockIdx.x, j = threadIdx.x;
    if (j < MCTX) pl[j] = P[(long long)b * MCTX + j];
    __syncthreads();
    const float* Ub = U + (long long)b * MCTX * DH;
    float acc = 0.0f;
    for (int m = 0; m < MCTX; m++) acc += pl[m] * Ub[(long long)m * DH + j];
    u[(long long)b * DH + j] = acc;
}

extern "C" __global__ __launch_bounds__(256)
void mixprep_k(float* h2, const float* ybar, const float* Wy, const float* by,
               const float* bt2)
{
    int b = blockIdx.x, d = threadIdx.x;
    h2[(long long)b * DM + d] += ybar[b] * Wy[d] + by[d] + bt2[d];
}

extern "C" __global__ __launch_bounds__(256)
void head_k(const float* X, const float* g, const float* bln, const float* Wh,
            const float* bh, float* out)
{
    __shared__ float sred[256];
    int r = blockIdx.x, t = threadIdx.x;
    float x = X[(long long)r * DM + t];
    sred[t] = x; __syncthreads();
    for (int s = 128; s > 0; s >>= 1) { if (t < s) sred[t] += sred[t + s]; __syncthreads(); }
    float mu = sred[0] * (1.0f / DM); __syncthreads();
    float d = x - mu;
    sred[t] = d * d; __syncthreads();
    for (int s = 128; s > 0; s >>= 1) { if (t < s) sred[t] += sred[t + s]; __syncthreads(); }
    float var = sred[0] * (1.0f / DM); __syncthreads();
    float ln = d * rsqrtf(var + LNEPS) * g[t] + bln[t];
    float rl = (ln > 0.0f) ? ln : 0.0f;
    sred[t] = rl * Wh[t]; __syncthreads();
    for (int s = 128; s > 0; s >>= 1) { if (t < s) sred[t] += sred[t + s]; __syncthreads(); }
    if (t == 0) out[r] = sred[0] + bh[0];
}

extern "C" void kernel_launch(void* const* d_in, const int* in_sizes, int n_in,
                              void* d_out, int out_size, void* d_ws, size_t ws_size,
                              hipStream_t stream)
{
    const float* x_num  = (const float*)d_in[0];
    const float* cand_x = (const float*)d_in[1];
    const float* cand_y = (const float*)d_in[2];
    /* d_in[3] = context_size (int scalar) == 96 */
    const float* W_in = (const float*)d_in[4];
    const float* b_in = (const float*)d_in[5];
    const float* We1  = (const float*)d_in[6];
    const float* be1  = (const float*)d_in[7];
    const float* We2  = (const float*)d_in[8];
    const float* be2  = (const float*)d_in[9];
    const float* g_m  = (const float*)d_in[10];
    const float* b_m  = (const float*)d_in[11];
    const float* Ws   = (const float*)d_in[12];
    const float* bs   = (const float*)d_in[13];
    const float* Wy   = (const float*)d_in[14];
    const float* by   = (const float*)d_in[15];
    const float* Wt1  = (const float*)d_in[16];
    const float* Wt2  = (const float*)d_in[17];
    const float* bt2  = (const float*)d_in[18];
    const float* Wp1  = (const float*)d_in[19];
    const float* bp1  = (const float*)d_in[20];
    const float* Wp2  = (const float*)d_in[21];
    const float* bp2  = (const float*)d_in[22];
    const float* g_h  = (const float*)d_in[23];
    const float* b_h  = (const float*)d_in[24];
    const float* Wh   = (const float*)d_in[25];
    const float* bh   = (const float*)d_in[26];
    float* out = (float*)d_out;

    const int EC = 6250;    /* candidate-encode rows per chunk (16 chunks) */
    const int QS = 128;     /* sim queries per chunk (8 chunks)            */
    const int VC = 64;      /* value queries per chunk (16 chunks)         */

    char* p = (char*)d_ws;
    float* HQ1 = (float*)p; p += (long long)NB * DM * 4;
    float* HQ2 = (float*)p; p += (long long)NB * DM * 4;
    float* LNQ = (float*)p; p += (long long)NB * DM * 4;
    float* KQ  = (float*)p; p += (long long)NB * DM * 4;
    float* TQ  = (float*)p; p += (long long)NB * DH * 4;
    float* UQv = (float*)p; p += (long long)NB * DH * 4;
    float* XQ  = (float*)p; p += (long long)NB * DM * 4;
    float* XQ2 = (float*)p; p += (long long)NB * DM * 4;
    float* YB  = (float*)p; p += (long long)NB * 4;
    float* KC  = (float*)p; p += (long long)NCAND * DM * 4;
    float* SC  = (float*)p; p += (long long)NCAND * 4;
    int*   IDX = (int*)p;   p += (long long)NB * MCTX * 4;
    float* PRB = (float*)p; p += (long long)NB * MCTX * 4;
    float* Hc  = (float*)p; p += (long long)EC * DM * 4;
    float* Tc  = (float*)p; p += (long long)EC * DH * 4;
    float* H2c = (float*)p; p += (long long)EC * DM * 4;
    float* Sb  = (float*)p; p += (long long)QS * NCAND * 4;
    float* Db  = (float*)p; p += (long long)VC * MCTX * DM * 4;
    float* Ub  = (float*)p; p += (long long)VC * MCTX * DH * 4;
    float* LNc = Hc;   /* Hc dead after the We2 GEMM */

    dim3 blk(256);

    /* sentinel: distinguishes "kernels never ran" (absmax 3.0) from
       "pipeline broke midway" (absmax ~777) in the next round's report */
    fill_out_k<<<dim3((NB + 255) / 256), blk, 0, stream>>>(out, NB);

    /* ---- query encode ---- */
    gemm128<<<dim3(DM / 128, NB / 128), blk, 0, stream>>>(
        x_num, W_in, HQ1, b_in, (const float*)0, (const float*)0, NB, DM, DNUM, 0, 0, 0);
    gemm128<<<dim3(DH / 128, NB / 128), blk, 0, stream>>>(
        HQ1, We1, TQ, be1, (const float*)0, (const float*)0, NB, DH, DM, 0, 1, 0);
    gemm128<<<dim3(DM / 128, NB / 128), blk, 0, stream>>>(
        TQ, We2, HQ2, be2, HQ1, (const float*)0, NB, DM, DH, 0, 0, 0);
    ln256<<<dim3(NB), blk, 0, stream>>>(HQ2, LNQ, g_m, b_m);
    gemm128<<<dim3(DM / 128, NB / 128), blk, 0, stream>>>(
        LNQ, Ws, KQ, bs, (const float*)0, (const float*)0, NB, DM, DM, 0, 0, 0);

    /* ---- candidate encode (16 chunks of 6250 rows) ---- */
    for (int c0 = 0; c0 < NCAND; c0 += EC) {
        const float* Xc = cand_x + (long long)c0 * DNUM;
        gemm128<<<dim3(DM / 128, (EC + 127) / 128), blk, 0, stream>>>(
            Xc, W_in, Hc, b_in, (const float*)0, (const float*)0, EC, DM, DNUM, 0, 0, 0);
        gemm128<<<dim3(DH / 128, (EC + 127) / 128), blk, 0, stream>>>(
            Hc, We1, Tc, be1, (const float*)0, (const float*)0, EC, DH, DM, 0, 1, 0);
        gemm128<<<dim3(DM / 128, (EC + 127) / 128), blk, 0, stream>>>(
            Tc, We2, H2c, be2, Hc, (const float*)0, EC, DM, DH, 0, 0, 0);
        ln256<<<dim3(EC), blk, 0, stream>>>(H2c, LNc, g_m, b_m);
        gemm128<<<dim3(DM / 128, (EC + 127) / 128), blk, 0, stream>>>(
            LNc, Ws, KC + (long long)c0 * DM, bs, (const float*)0, (const float*)0, EC, DM, DM, 0, 0, 0);
    }
    snorm_k<<<dim3(NCAND), blk, 0, stream>>>(KC, SC);

    /* ---- sim (2*k.ck - ||ck||^2; row-constant ||k||^2 dropped: invariant
            under top-k and softmax) + exact top-96 ---- */
    for (int q0 = 0; q0 < NB; q0 += QS) {
        gemm128<<<dim3((NCAND + 127) / 128, QS / 128), blk, 0, stream>>>(
            KQ + (long long)q0 * DM, KC, Sb, (const float*)0, (const float*)0, SC,
            QS, NCAND, DM, 1, 0, 1);
        topk_k<<<dim3(QS), blk, 0, stream>>>(Sb, q0, IDX, PRB);
    }

    /* ---- value aggregation: sum_m p_m * v_m, with linear ops pulled out:
            = ybar*Wy + by + bt2 + (sum_m p_m ReLU(D_m@Wt1)) @ Wt2 ---- */
    ybar_k<<<dim3(NB), blk, 0, stream>>>(PRB, IDX, cand_y, YB);
    for (int v0 = 0; v0 < NB; v0 += VC) {
        gatherD_k<<<dim3(VC * MCTX), blk, 0, stream>>>(
            KQ + (long long)v0 * DM, KC, IDX + (long long)v0 * MCTX, Db);
        gemm128<<<dim3(DH / 128, (VC * MCTX) / 128), blk, 0, stream>>>(
            Db, Wt1, Ub, (const float*)0, (const float*)0, (const float*)0,
            VC * MCTX, DH, DM, 0, 1, 0);
        wsum_k<<<dim3(VC), dim3(512), 0, stream>>>(
            Ub, PRB + (long long)v0 * MCTX, UQv + (long long)v0 * DH);
    }
    mixprep_k<<<dim3(NB), blk, 0, stream>>>(HQ2, YB, Wy, by, bt2);
    gemm128<<<dim3(DM / 128, NB / 128), blk, 0, stream>>>(
        UQv, Wt2, XQ, (const float*)0, HQ2, (const float*)0, NB, DM, DH, 0, 0, 0);

    /* ---- predictor block + head ---- */
    gemm128<<<dim3(DH / 128, NB / 128), blk, 0, stream>>>(
        XQ, Wp1, TQ, bp1, (const float*)0, (const float*)0, NB, DH, DM, 0, 1, 0);
    gemm128<<<dim3(DM / 128, NB / 128), blk, 0, stream>>>(
        TQ, Wp2, XQ2, bp2, XQ, (const float*)0, NB, DM, DH, 0, 0, 0);
    head_k<<<dim3(NB), blk, 0, stream>>>(XQ2, g_h, b_h, Wh, bh, out);
}

// Round 5
// 7018.253 us; speedup vs baseline: 2.0296x; 2.0296x over previous
//
#include <hip/hip_runtime.h>
#include <stdint.h>

#define NCAND 100000
#define NB    1024
#define DNUM  96
#define DM    256
#define DH    512
#define MCTX  96
#define LNEPS 1e-5f

typedef __bf16 bf16x8 __attribute__((ext_vector_type(8)));
typedef float  f32x4  __attribute__((ext_vector_type(4)));

__device__ __forceinline__ unsigned short f2bf(float x)
{
    unsigned u = __float_as_uint(x);
    unsigned r = u + 0x7FFFu + ((u >> 16) & 1u);   /* round-to-nearest-even */
    return (unsigned short)(r >> 16);
}
__device__ __forceinline__ float bf2f_bits(unsigned short h)
{
    return __uint_as_float(((unsigned)h) << 16);
}

extern "C" __global__ __launch_bounds__(256)
void fill_out_k(float* out, int n)
{
    int i = blockIdx.x * 256 + threadIdx.x;
    if (i < n) out[i] = 777.0f;
}

/* ---------------- split-bf16 MFMA GEMM ----------------
   C[M,N] = A[M,K] @ B (+bias, +resid, ReLU) or sim-epilogue (2*acc - colb[n]).
   A,B,C are f32 in global. Internally A,B are split a = hi + lo (bf16 each);
   acc += Ahi*Bhi + Ahi*Blo + Alo*Bhi  via v_mfma_f32_16x16x32_bf16.
   Relative precision ~1e-4 (exact enough for top-k semantics downstream).
   btrans: B is [N,K] row-major; else [K,N] row-major. K % 32 == 0 required. */
extern "C" __global__ __launch_bounds__(256)
void gemm_mfma(const float* A, const float* B, float* C,
               const float* bias, const float* resid, const float* colb,
               int M, int N, int K, int btrans, int dorelu, int simepi)
{
    __shared__ unsigned short Ah[128][40];
    __shared__ unsigned short Al[128][40];
    __shared__ unsigned short Bh[128][40];
    __shared__ unsigned short Bl[128][40];
    int t = threadIdx.x;
    int m0 = blockIdx.y * 128;
    int n0 = blockIdx.x * 128;
    int wave = t >> 6, lane = t & 63;
    int lm = lane & 15;            /* row/col within 16-tile  */
    int lk = (lane >> 4) * 8;      /* k-offset within 32      */
    int mw = (wave & 1) * 64, nw = (wave >> 1) * 64;

    f32x4 acc[4][4];
    for (int i = 0; i < 4; i++)
        for (int j = 0; j < 4; j++)
            for (int e = 0; e < 4; e++) acc[i][j][e] = 0.0f;

    for (int k0 = 0; k0 < K; k0 += 32) {
        float av[4][4], bv[4][4];
        /* A: rows m0..+127, k0..+31.  idx -> row=idx>>3, k-seg=(idx&7)*4 */
        for (int rep = 0; rep < 4; rep++) {
            int idx = rep * 256 + t;
            int r = idx >> 3, seg = idx & 7;
            int row = m0 + r;
            if (row < M) {
                const float* p = A + (long long)row * K + k0 + seg * 4;
                av[rep][0] = p[0]; av[rep][1] = p[1]; av[rep][2] = p[2]; av[rep][3] = p[3];
            } else {
                av[rep][0] = av[rep][1] = av[rep][2] = av[rep][3] = 0.0f;
            }
        }
        if (btrans) {
            /* B[N,K]: rows n0..+127, k0..+31 -> Bh[n][k] direct */
            for (int rep = 0; rep < 4; rep++) {
                int idx = rep * 256 + t;
                int r = idx >> 3, seg = idx & 7;
                int row = n0 + r;
                if (row < N) {
                    const float* p = B + (long long)row * K + k0 + seg * 4;
                    bv[rep][0] = p[0]; bv[rep][1] = p[1]; bv[rep][2] = p[2]; bv[rep][3] = p[3];
                } else {
                    bv[rep][0] = bv[rep][1] = bv[rep][2] = bv[rep][3] = 0.0f;
                }
            }
        } else {
            /* B[K,N]: k0..+31, n0..+127.  idx -> kk=idx>>5, n-seg=(idx&31)*4 */
            for (int rep = 0; rep < 4; rep++) {
                int idx = rep * 256 + t;
                int kk = idx >> 5, seg = idx & 31;
                int col = n0 + seg * 4;
                const float* p = B + (long long)(k0 + kk) * N + col;
                for (int e = 0; e < 4; e++)
                    bv[rep][e] = (col + e < N) ? p[e] : 0.0f;
            }
        }
        __syncthreads();   /* protect previous iteration's LDS reads */
        for (int rep = 0; rep < 4; rep++) {
            int idx = rep * 256 + t;
            int r = idx >> 3, seg = idx & 7;
            for (int e = 0; e < 4; e++) {
                float x = av[rep][e];
                unsigned short h = f2bf(x);
                unsigned short l = f2bf(x - bf2f_bits(h));
                Ah[r][seg * 4 + e] = h;
                Al[r][seg * 4 + e] = l;
            }
        }
        if (btrans) {
            for (int rep = 0; rep < 4; rep++) {
                int idx = rep * 256 + t;
                int r = idx >> 3, seg = idx & 7;
                for (int e = 0; e < 4; e++) {
                    float x = bv[rep][e];
                    unsigned short h = f2bf(x);
                    unsigned short l = f2bf(x - bf2f_bits(h));
                    Bh[r][seg * 4 + e] = h;
                    Bl[r][seg * 4 + e] = l;
                }
            }
        } else {
            for (int rep = 0; rep < 4; rep++) {
                int idx = rep * 256 + t;
                int kk = idx >> 5, seg = idx & 31;
                for (int e = 0; e < 4; e++) {
                    float x = bv[rep][e];
                    unsigned short h = f2bf(x);
                    unsigned short l = f2bf(x - bf2f_bits(h));
                    Bh[seg * 4 + e][kk] = h;    /* store transposed: [n][k] */
                    Bl[seg * 4 + e][kk] = l;
                }
            }
        }
        __syncthreads();
        /* fragments: A[m][k]: m=lane&15, k=(lane>>4)*8+j ; B[k][n]: n=lane&15 */
        bf16x8 fah[4], fal[4], fbh[4], fbl[4];
        for (int i = 0; i < 4; i++) {
            fah[i] = *(const bf16x8*)(&Ah[mw + i * 16 + lm][lk]);
            fal[i] = *(const bf16x8*)(&Al[mw + i * 16 + lm][lk]);
        }
        for (int j = 0; j < 4; j++) {
            fbh[j] = *(const bf16x8*)(&Bh[nw + j * 16 + lm][lk]);
            fbl[j] = *(const bf16x8*)(&Bl[nw + j * 16 + lm][lk]);
        }
        for (int i = 0; i < 4; i++)
            for (int j = 0; j < 4; j++) {
                acc[i][j] = __builtin_amdgcn_mfma_f32_16x16x32_bf16(fah[i], fbh[j], acc[i][j], 0, 0, 0);
                acc[i][j] = __builtin_amdgcn_mfma_f32_16x16x32_bf16(fah[i], fbl[j], acc[i][j], 0, 0, 0);
                acc[i][j] = __builtin_amdgcn_mfma_f32_16x16x32_bf16(fal[i], fbh[j], acc[i][j], 0, 0, 0);
            }
    }
    /* C/D layout: col = lane&15, row = (lane>>4)*4 + reg */
    int rbase = (lane >> 4) * 4;
    for (int i = 0; i < 4; i++) {
        for (int j = 0; j < 4; j++) {
            int col = n0 + nw + j * 16 + lm;
            if (col >= N) continue;
            for (int r = 0; r < 4; r++) {
                int row = m0 + mw + i * 16 + rbase + r;
                if (row >= M) continue;
                float v = acc[i][j][r];
                if (simepi) {
                    v = 2.0f * v - colb[col];
                } else {
                    if (bias)  v += bias[col];
                    if (resid) v += resid[(long long)row * N + col];
                    if (dorelu && v < 0.0f) v = 0.0f;
                }
                C[(long long)row * N + col] = v;
            }
        }
    }
}

extern "C" __global__ __launch_bounds__(256)
void ln256(const float* X, float* Y, const float* g, const float* b)
{
    __shared__ float sred[256];
    int r = blockIdx.x, t = threadIdx.x;
    float x = X[(long long)r * DM + t];
    sred[t] = x; __syncthreads();
    for (int s = 128; s > 0; s >>= 1) { if (t < s) sred[t] += sred[t + s]; __syncthreads(); }
    float mu = sred[0] * (1.0f / DM); __syncthreads();
    float d = x - mu;
    sred[t] = d * d; __syncthreads();
    for (int s = 128; s > 0; s >>= 1) { if (t < s) sred[t] += sred[t + s]; __syncthreads(); }
    float var = sred[0] * (1.0f / DM);
    Y[(long long)r * DM + t] = d * rsqrtf(var + LNEPS) * g[t] + b[t];
}

extern "C" __global__ __launch_bounds__(256)
void snorm_k(const float* Kc, float* sc)
{
    __shared__ float sred[256];
    int c = blockIdx.x, t = threadIdx.x;
    float v = Kc[(long long)c * DM + t];
    sred[t] = v * v; __syncthreads();
    for (int s = 128; s > 0; s >>= 1) { if (t < s) sred[t] += sred[t + s]; __syncthreads(); }
    if (t == 0) sc[c] = sred[0];
}

__device__ unsigned fmapf(float f)
{
    unsigned u = __float_as_uint(f);
    return u ^ (unsigned)(((int)u >> 31) | (int)0x80000000);
}

/* exact top-96 (radix select 4x8-bit, full-32-bit tie handling, ties ->
   smallest index) + softmax. 1024 threads, float4 scans. */
extern "C" __global__ __launch_bounds__(1024)
void topk_k(const float* S, int q0, int* out_idx, float* out_p)
{
    int t = threadIdx.x;
    const float* row = S + (long long)blockIdx.x * NCAND;
    const float4* row4 = (const float4*)row;     /* NCAND % 4 == 0 */
    __shared__ int hist8[8][256];
    __shared__ unsigned sh_prefix;
    __shared__ int sh_want, cntG, cntE;
    __shared__ int   gidx[128];
    __shared__ float gval[128];
    __shared__ int   eqi[2048];
    __shared__ float vals[MCTX];
    __shared__ int   inds[MCTX];
    __shared__ float pr[MCTX];

    if (t == 0) { sh_prefix = 0u; sh_want = MCTX; cntG = 0; cntE = 0; }

    for (int lvl = 0; lvl < 4; lvl++) {
        int shift = 24 - 8 * lvl;
        for (int i = t; i < 2048; i += 1024) ((int*)hist8)[i] = 0;
        __syncthreads();
        unsigned prefix = sh_prefix;
        unsigned mask = (lvl == 0) ? 0u : (0xFFFFFFFFu << (shift + 8));
        int* hrow = hist8[t & 7];
        for (int c = t; c < NCAND / 4; c += 1024) {
            float4 v = row4[c];
            unsigned k0 = fmapf(v.x), k1 = fmapf(v.y), k2 = fmapf(v.z), k3 = fmapf(v.w);
            if ((k0 & mask) == prefix) atomicAdd(&hrow[(k0 >> shift) & 255], 1);
            if ((k1 & mask) == prefix) atomicAdd(&hrow[(k1 >> shift) & 255], 1);
            if ((k2 & mask) == prefix) atomicAdd(&hrow[(k2 >> shift) & 255], 1);
            if ((k3 & mask) == prefix) atomicAdd(&hrow[(k3 >> shift) & 255], 1);
        }
        __syncthreads();
        if (t < 256) {
            int s = 0;
            for (int g2 = 1; g2 < 8; g2++) s += hist8[g2][t];
            hist8[0][t] += s;
        }
        __syncthreads();
        if (t == 0) {
            int want = sh_want, cum = 0;
            for (int b2 = 255; b2 >= 0; b2--) {
                cum += hist8[0][b2];
                if (cum >= want) {
                    sh_want = want - (cum - hist8[0][b2]);
                    sh_prefix = prefix | ((unsigned)b2 << shift);
                    break;
                }
            }
        }
        __syncthreads();
    }
    unsigned T = sh_prefix;
    for (int c = t; c < NCAND / 4; c += 1024) {
        float4 v = row4[c];
        float  vv[4]; vv[0] = v.x; vv[1] = v.y; vv[2] = v.z; vv[3] = v.w;
        for (int e = 0; e < 4; e++) {
            unsigned key = fmapf(vv[e]);
            if (key > T) {
                int p = atomicAdd(&cntG, 1);
                if (p < 128) { gidx[p] = c * 4 + e; gval[p] = vv[e]; }
            } else if (key == T) {
                int p = atomicAdd(&cntE, 1);
                if (p < 2048) eqi[p] = c * 4 + e;
            }
        }
    }
    __syncthreads();
    if (t == 0) {
        int nG = cntG; if (nG > MCTX) nG = MCTX;
        int nE = cntE; if (nE > 2048) nE = 2048;
        int need = MCTX - nG;
        for (int i = 0; i < nG; i++) { inds[i] = gidx[i]; vals[i] = gval[i]; }
        for (int s = 0; s < need; s++) {
            int best = 0x7FFFFFFF, bp = -1;
            for (int e = 0; e < nE; e++) if (eqi[e] < best) { best = eqi[e]; bp = e; }
            if (bp >= 0) { eqi[bp] = 0x7FFFFFFF; inds[nG + s] = best; vals[nG + s] = row[best]; }
            else         { inds[nG + s] = 0;     vals[nG + s] = -3.0e38f; }
        }
        float mx = -3.4e38f;
        for (int i = 0; i < MCTX; i++) if (vals[i] > mx) mx = vals[i];
        float sum = 0.0f;
        for (int i = 0; i < MCTX; i++) { float e = expf(vals[i] - mx); pr[i] = e; sum += e; }
        float inv = 1.0f / sum;
        for (int i = 0; i < MCTX; i++) pr[i] *= inv;
    }
    __syncthreads();
    if (t < MCTX) {
        long long o = (long long)(q0 + blockIdx.x) * MCTX + t;
        out_idx[o] = inds[t];
        out_p[o]   = pr[t];
    }
}

extern "C" __global__ __launch_bounds__(256)
void gatherD_k(const float* kq, const float* Kc, const int* idx, float* D)
{
    int r = blockIdx.x, t = threadIdx.x;
    int b = r / MCTX;
    int ci = idx[r];
    D[(long long)r * DM + t] = kq[(long long)b * DM + t] - Kc[(long long)ci * DM + t];
}

extern "C" __global__ __launch_bounds__(256)
void ybar_k(const float* P, const int* idx, const float* y, float* ybar)
{
    __shared__ float sred[256];
    int b = blockIdx.x, t = threadIdx.x;
    float v = 0.0f;
    if (t < MCTX) v = P[(long long)b * MCTX + t] * y[idx[(long long)b * MCTX + t]];
    sred[t] = v; __syncthreads();
    for (int s = 128; s > 0; s >>= 1) { if (t < s) sred[t] += sred[t + s]; __syncthreads(); }
    if (t == 0) ybar[b] = sred[0];
}

extern "C" __global__ __launch_bounds__(512)
void wsum_k(const float* U, const float* P, float* u)
{
    __shared__ float pl[MCTX];
    int b = blockIdx.x, j = threadIdx.x;
    if (j < MCTX) pl[j] = P[(long long)b * MCTX + j];
    __syncthreads();
    const float* Ub = U + (long long)b * MCTX * DH;
    float acc = 0.0f;
    for (int m = 0; m < MCTX; m++) acc += pl[m] * Ub[(long long)m * DH + j];
    u[(long long)b * DH + j] = acc;
}

extern "C" __global__ __launch_bounds__(256)
void mixprep_k(float* h2, const float* ybar, const float* Wy, const float* by,
               const float* bt2)
{
    int b = blockIdx.x, d = threadIdx.x;
    h2[(long long)b * DM + d] += ybar[b] * Wy[d] + by[d] + bt2[d];
}

extern "C" __global__ __launch_bounds__(256)
void head_k(const float* X, const float* g, const float* bln, const float* Wh,
            const float* bh, float* out)
{
    __shared__ float sred[256];
    int r = blockIdx.x, t = threadIdx.x;
    float x = X[(long long)r * DM + t];
    sred[t] = x; __syncthreads();
    for (int s = 128; s > 0; s >>= 1) { if (t < s) sred[t] += sred[t + s]; __syncthreads(); }
    float mu = sred[0] * (1.0f / DM); __syncthreads();
    float d = x - mu;
    sred[t] = d * d; __syncthreads();
    for (int s = 128; s > 0; s >>= 1) { if (t < s) sred[t] += sred[t + s]; __syncthreads(); }
    float var = sred[0] * (1.0f / DM); __syncthreads();
    float ln = d * rsqrtf(var + LNEPS) * g[t] + bln[t];
    float rl = (ln > 0.0f) ? ln : 0.0f;
    sred[t] = rl * Wh[t]; __syncthreads();
    for (int s = 128; s > 0; s >>= 1) { if (t < s) sred[t] += sred[t + s]; __syncthreads(); }
    if (t == 0) out[r] = sred[0] + bh[0];
}

extern "C" void kernel_launch(void* const* d_in, const int* in_sizes, int n_in,
                              void* d_out, int out_size, void* d_ws, size_t ws_size,
                              hipStream_t stream)
{
    const float* x_num  = (const float*)d_in[0];
    const float* cand_x = (const float*)d_in[1];
    const float* cand_y = (const float*)d_in[2];
    /* d_in[3] = context_size (int scalar) == 96 */
    const float* W_in = (const float*)d_in[4];
    const float* b_in = (const float*)d_in[5];
    const float* We1  = (const float*)d_in[6];
    const float* be1  = (const float*)d_in[7];
    const float* We2  = (const float*)d_in[8];
    const float* be2  = (const float*)d_in[9];
    const float* g_m  = (const float*)d_in[10];
    const float* b_m  = (const float*)d_in[11];
    const float* Ws   = (const float*)d_in[12];
    const float* bs   = (const float*)d_in[13];
    const float* Wy   = (const float*)d_in[14];
    const float* by   = (const float*)d_in[15];
    const float* Wt1  = (const float*)d_in[16];
    const float* Wt2  = (const float*)d_in[17];
    const float* bt2  = (const float*)d_in[18];
    const float* Wp1  = (const float*)d_in[19];
    const float* bp1  = (const float*)d_in[20];
    const float* Wp2  = (const float*)d_in[21];
    const float* bp2  = (const float*)d_in[22];
    const float* g_h  = (const float*)d_in[23];
    const float* b_h  = (const float*)d_in[24];
    const float* Wh   = (const float*)d_in[25];
    const float* bh   = (const float*)d_in[26];
    float* out = (float*)d_out;

    const int EC = 6250;    /* candidate-encode rows per chunk (16 chunks) */
    const int QS = 128;     /* sim queries per chunk (8 chunks)            */
    const int VC = 64;      /* value queries per chunk (16 chunks)         */

    char* p = (char*)d_ws;
    float* HQ1 = (float*)p; p += (long long)NB * DM * 4;
    float* HQ2 = (float*)p; p += (long long)NB * DM * 4;
    float* LNQ = (float*)p; p += (long long)NB * DM * 4;
    float* KQ  = (float*)p; p += (long long)NB * DM * 4;
    float* TQ  = (float*)p; p += (long long)NB * DH * 4;
    float* UQv = (float*)p; p += (long long)NB * DH * 4;
    float* XQ  = (float*)p; p += (long long)NB * DM * 4;
    float* XQ2 = (float*)p; p += (long long)NB * DM * 4;
    float* YB  = (float*)p; p += (long long)NB * 4;
    float* KC  = (float*)p; p += (long long)NCAND * DM * 4;
    float* SC  = (float*)p; p += (long long)NCAND * 4;
    int*   IDX = (int*)p;   p += (long long)NB * MCTX * 4;
    float* PRB = (float*)p; p += (long long)NB * MCTX * 4;
    float* Hc  = (float*)p; p += (long long)EC * DM * 4;
    float* Tc  = (float*)p; p += (long long)EC * DH * 4;
    float* H2c = (float*)p; p += (long long)EC * DM * 4;
    float* Sb  = (float*)p; p += (long long)QS * NCAND * 4;
    float* Db  = (float*)p; p += (long long)VC * MCTX * DM * 4;
    float* Ub  = (float*)p; p += (long long)VC * MCTX * DH * 4;
    float* LNc = Hc;   /* Hc dead after the We2 GEMM */

    dim3 blk(256);

    fill_out_k<<<dim3((NB + 255) / 256), blk, 0, stream>>>(out, NB);

    /* ---- query encode ---- */
    gemm_mfma<<<dim3(DM / 128, NB / 128), blk, 0, stream>>>(
        x_num, W_in, HQ1, b_in, (const float*)0, (const float*)0, NB, DM, DNUM, 0, 0, 0);
    gemm_mfma<<<dim3(DH / 128, NB / 128), blk, 0, stream>>>(
        HQ1, We1, TQ, be1, (const float*)0, (const float*)0, NB, DH, DM, 0, 1, 0);
    gemm_mfma<<<dim3(DM / 128, NB / 128), blk, 0, stream>>>(
        TQ, We2, HQ2, be2, HQ1, (const float*)0, NB, DM, DH, 0, 0, 0);
    ln256<<<dim3(NB), blk, 0, stream>>>(HQ2, LNQ, g_m, b_m);
    gemm_mfma<<<dim3(DM / 128, NB / 128), blk, 0, stream>>>(
        LNQ, Ws, KQ, bs, (const float*)0, (const float*)0, NB, DM, DM, 0, 0, 0);

    /* ---- candidate encode (16 chunks of 6250 rows) ---- */
    for (int c0 = 0; c0 < NCAND; c0 += EC) {
        const float* Xc = cand_x + (long long)c0 * DNUM;
        gemm_mfma<<<dim3(DM / 128, (EC + 127) / 128), blk, 0, stream>>>(
            Xc, W_in, Hc, b_in, (const float*)0, (const float*)0, EC, DM, DNUM, 0, 0, 0);
        gemm_mfma<<<dim3(DH / 128, (EC + 127) / 128), blk, 0, stream>>>(
            Hc, We1, Tc, be1, (const float*)0, (const float*)0, EC, DH, DM, 0, 1, 0);
        gemm_mfma<<<dim3(DM / 128, (EC + 127) / 128), blk, 0, stream>>>(
            Tc, We2, H2c, be2, Hc, (const float*)0, EC, DM, DH, 0, 0, 0);
        ln256<<<dim3(EC), blk, 0, stream>>>(H2c, LNc, g_m, b_m);
        gemm_mfma<<<dim3(DM / 128, (EC + 127) / 128), blk, 0, stream>>>(
            LNc, Ws, KC + (long long)c0 * DM, bs, (const float*)0, (const float*)0, EC, DM, DM, 0, 0, 0);
    }
    snorm_k<<<dim3(NCAND), blk, 0, stream>>>(KC, SC);

    /* ---- sim (2*k.ck - ||ck||^2) + exact top-96 ---- */
    for (int q0 = 0; q0 < NB; q0 += QS) {
        gemm_mfma<<<dim3((NCAND + 127) / 128, QS / 128), blk, 0, stream>>>(
            KQ + (long long)q0 * DM, KC, Sb, (const float*)0, (const float*)0, SC,
            QS, NCAND, DM, 1, 0, 1);
        topk_k<<<dim3(QS), dim3(1024), 0, stream>>>(Sb, q0, IDX, PRB);
    }

    /* ---- value aggregation ---- */
    ybar_k<<<dim3(NB), blk, 0, stream>>>(PRB, IDX, cand_y, YB);
    for (int v0 = 0; v0 < NB; v0 += VC) {
        gatherD_k<<<dim3(VC * MCTX), blk, 0, stream>>>(
            KQ + (long long)v0 * DM, KC, IDX + (long long)v0 * MCTX, Db);
        gemm_mfma<<<dim3(DH / 128, (VC * MCTX) / 128), blk, 0, stream>>>(
            Db, Wt1, Ub, (const float*)0, (const float*)0, (const float*)0,
            VC * MCTX, DH, DM, 0, 1, 0);
        wsum_k<<<dim3(VC), dim3(512), 0, stream>>>(
            Ub, PRB + (long long)v0 * MCTX, UQv + (long long)v0 * DH);
    }
    mixprep_k<<<dim3(NB), blk, 0, stream>>>(HQ2, YB, Wy, by, bt2);
    gemm_mfma<<<dim3(DM / 128, NB / 128), blk, 0, stream>>>(
        UQv, Wt2, XQ, (const float*)0, HQ2, (const float*)0, NB, DM, DH, 0, 0, 0);

    /* ---- predictor block + head ---- */
    gemm_mfma<<<dim3(DH / 128, NB / 128), blk, 0, stream>>>(
        XQ, Wp1, TQ, bp1, (const float*)0, (const float*)0, NB, DH, DM, 0, 1, 0);
    gemm_mfma<<<dim3(DM / 128, NB / 128), blk, 0, stream>>>(
        TQ, Wp2, XQ2, bp2, XQ, (const float*)0, NB, DM, DH, 0, 0, 0);
    head_k<<<dim3(NB), blk, 0, stream>>>(XQ2, g_h, b_h, Wh, bh, out);
}

// Round 6
// 4819.832 us; speedup vs baseline: 2.9553x; 1.4561x over previous
//
#include <hip/hip_runtime.h>
#include <stdint.h>

#define NCAND 100000
#define NB    1024
#define DNUM  96
#define DM    256
#define DH    512
#define MCTX  96
#define LNEPS 1e-5f

typedef __bf16 bf16x8 __attribute__((ext_vector_type(8)));
typedef float  f32x4  __attribute__((ext_vector_type(4)));
typedef unsigned short u16x8 __attribute__((ext_vector_type(8)));

__device__ __forceinline__ unsigned short f2bf(float x)
{
    unsigned u = __float_as_uint(x);
    unsigned r = u + 0x7FFFu + ((u >> 16) & 1u);   /* RNE */
    return (unsigned short)(r >> 16);
}
__device__ __forceinline__ float bfbits(unsigned short h)
{
    return __uint_as_float(((unsigned)h) << 16);
}

/* ---- split f32 -> (hi,lo) bf16, same layout ---- */
extern "C" __global__ __launch_bounds__(256)
void split_k(const float* X, unsigned short* Xh, unsigned short* Xl, long long n)
{
    long long i = (long long)blockIdx.x * 256 + threadIdx.x;
    if (i < n) {
        float x = X[i];
        unsigned short h = f2bf(x);
        Xh[i] = h;
        Xl[i] = f2bf(x - bfbits(h));
    }
}

/* ---- split + transpose: W[Kd,Nd] -> T[Nd,Kd] ---- */
extern "C" __global__ __launch_bounds__(256)
void splitT_k(const float* W, unsigned short* Th, unsigned short* Tl, int Kd, int Nd)
{
    int i = blockIdx.x * 256 + threadIdx.x;
    if (i < Kd * Nd) {
        int k = i / Nd, n2 = i - k * Nd;
        float x = W[i];
        unsigned short h = f2bf(x);
        Th[(long long)n2 * Kd + k] = h;
        Tl[(long long)n2 * Kd + k] = f2bf(x - bfbits(h));
    }
}

/* ---------------- split-bf16 MFMA GEMM ----------------
   C[M,N] = A[M,K] @ B^T where A[M,K], B[N,K] are pre-split (hi,lo bf16).
   acc = Ah*Bh + Ah*Bl + Al*Bh  (3-pass, f32 accumulate, rel err ~1e-4).
   Epilogue: +bias(f32), +resid(split pair), ReLU, or simepi (2*acc-colb).
   Outputs: Cf (f32) and/or (Ch,Cl) split. K % 32 == 0. */
extern "C" __global__ __launch_bounds__(256)
void gemm_sp(const unsigned short* Ah, const unsigned short* Al,
             const unsigned short* Bh, const unsigned short* Bl,
             float* Cf, unsigned short* Ch, unsigned short* Cl,
             const float* bias, const unsigned short* Rh, const unsigned short* Rl,
             const float* colb,
             int M, int N, int K, int dorelu, int simepi)
{
    __shared__ unsigned short Ahs[128][40];
    __shared__ unsigned short Als[128][40];
    __shared__ unsigned short Bhs[128][40];
    __shared__ unsigned short Bls[128][40];
    int t = threadIdx.x;
    int m0 = blockIdx.y * 128;
    int n0 = blockIdx.x * 128;
    int wave = t >> 6, lane = t & 63;
    int lm = lane & 15;
    int lk = (lane >> 4) * 8;
    int mw = (wave & 1) * 64, nw = (wave >> 1) * 64;

    f32x4 acc[4][4];
    for (int i = 0; i < 4; i++)
        for (int j = 0; j < 4; j++)
            for (int e = 0; e < 4; e++) acc[i][j][e] = 0.0f;

    int r  = t >> 1;
    int sg = (t & 1) * 16;

    for (int k0 = 0; k0 < K; k0 += 32) {
        u16x8 ah0 = {0,0,0,0,0,0,0,0}, ah1 = ah0, al0 = ah0, al1 = ah0;
        u16x8 bh0 = ah0, bh1 = ah0, bl0 = ah0, bl1 = ah0;
        int arow = m0 + r;
        if (arow < M) {
            const u16x8* ph = (const u16x8*)(Ah + (long long)arow * K + k0 + sg);
            const u16x8* pl = (const u16x8*)(Al + (long long)arow * K + k0 + sg);
            ah0 = ph[0]; ah1 = ph[1]; al0 = pl[0]; al1 = pl[1];
        }
        int brow = n0 + r;
        if (brow < N) {
            const u16x8* ph = (const u16x8*)(Bh + (long long)brow * K + k0 + sg);
            const u16x8* pl = (const u16x8*)(Bl + (long long)brow * K + k0 + sg);
            bh0 = ph[0]; bh1 = ph[1]; bl0 = pl[0]; bl1 = pl[1];
        }
        __syncthreads();    /* protect previous iteration's LDS reads */
        *(u16x8*)&Ahs[r][sg]     = ah0;  *(u16x8*)&Ahs[r][sg + 8] = ah1;
        *(u16x8*)&Als[r][sg]     = al0;  *(u16x8*)&Als[r][sg + 8] = al1;
        *(u16x8*)&Bhs[r][sg]     = bh0;  *(u16x8*)&Bhs[r][sg + 8] = bh1;
        *(u16x8*)&Bls[r][sg]     = bl0;  *(u16x8*)&Bls[r][sg + 8] = bl1;
        __syncthreads();
        bf16x8 fah[4], fal[4], fbh[4], fbl[4];
        for (int i = 0; i < 4; i++) {
            fah[i] = *(const bf16x8*)(&Ahs[mw + i * 16 + lm][lk]);
            fal[i] = *(const bf16x8*)(&Als[mw + i * 16 + lm][lk]);
        }
        for (int j = 0; j < 4; j++) {
            fbh[j] = *(const bf16x8*)(&Bhs[nw + j * 16 + lm][lk]);
            fbl[j] = *(const bf16x8*)(&Bls[nw + j * 16 + lm][lk]);
        }
        for (int i = 0; i < 4; i++)
            for (int j = 0; j < 4; j++) {
                acc[i][j] = __builtin_amdgcn_mfma_f32_16x16x32_bf16(fah[i], fbh[j], acc[i][j], 0, 0, 0);
                acc[i][j] = __builtin_amdgcn_mfma_f32_16x16x32_bf16(fah[i], fbl[j], acc[i][j], 0, 0, 0);
                acc[i][j] = __builtin_amdgcn_mfma_f32_16x16x32_bf16(fal[i], fbh[j], acc[i][j], 0, 0, 0);
            }
    }
    /* C/D layout: col = lane&15, row = (lane>>4)*4 + reg */
    int rbase = (lane >> 4) * 4;
    for (int i = 0; i < 4; i++) {
        for (int j = 0; j < 4; j++) {
            int col = n0 + nw + j * 16 + lm;
            if (col >= N) continue;
            for (int e = 0; e < 4; e++) {
                int row = m0 + mw + i * 16 + rbase + e;
                if (row >= M) continue;
                long long idx = (long long)row * N + col;
                float v = acc[i][j][e];
                if (simepi) {
                    v = 2.0f * v - colb[col];
                } else {
                    if (bias) v += bias[col];
                    if (Rh)   v += bfbits(Rh[idx]) + bfbits(Rl[idx]);
                    if (dorelu && v < 0.0f) v = 0.0f;
                }
                if (Cf) Cf[idx] = v;
                if (Ch) {
                    unsigned short h = f2bf(v);
                    Ch[idx] = h;
                    Cl[idx] = f2bf(v - bfbits(h));
                }
            }
        }
    }
}

/* ---- LayerNorm on split input, split output (rows of 256) ---- */
extern "C" __global__ __launch_bounds__(256)
void ln_sp(const unsigned short* Xh, const unsigned short* Xl,
           unsigned short* Yh, unsigned short* Yl, const float* g, const float* b)
{
    __shared__ float sred[256];
    int r = blockIdx.x, t = threadIdx.x;
    long long idx = (long long)r * DM + t;
    float x = bfbits(Xh[idx]) + bfbits(Xl[idx]);
    sred[t] = x; __syncthreads();
    for (int s = 128; s > 0; s >>= 1) { if (t < s) sred[t] += sred[t + s]; __syncthreads(); }
    float mu = sred[0] * (1.0f / DM); __syncthreads();
    float d = x - mu;
    sred[t] = d * d; __syncthreads();
    for (int s = 128; s > 0; s >>= 1) { if (t < s) sred[t] += sred[t + s]; __syncthreads(); }
    float var = sred[0] * (1.0f / DM);
    float y = d * rsqrtf(var + LNEPS) * g[t] + b[t];
    unsigned short h = f2bf(y);
    Yh[idx] = h;
    Yl[idx] = f2bf(y - bfbits(h));
}

extern "C" __global__ __launch_bounds__(256)
void snorm_sp(const unsigned short* Kh, const unsigned short* Kl, float* sc)
{
    __shared__ float sred[256];
    int c = blockIdx.x, t = threadIdx.x;
    long long idx = (long long)c * DM + t;
    float v = bfbits(Kh[idx]) + bfbits(Kl[idx]);
    sred[t] = v * v; __syncthreads();
    for (int s = 128; s > 0; s >>= 1) { if (t < s) sred[t] += sred[t + s]; __syncthreads(); }
    if (t == 0) sc[c] = sred[0];
}

__device__ unsigned fmapf(float f)
{
    unsigned u = __float_as_uint(f);
    return u ^ (unsigned)(((int)u >> 31) | (int)0x80000000);
}

/* exact top-96 (radix select 4x8-bit, ties -> smallest index) + softmax */
extern "C" __global__ __launch_bounds__(1024)
void topk_k(const float* S, int q0, int* out_idx, float* out_p)
{
    int t = threadIdx.x;
    const float* row = S + (long long)blockIdx.x * NCAND;
    const float4* row4 = (const float4*)row;
    __shared__ int hist8[8][256];
    __shared__ unsigned sh_prefix;
    __shared__ int sh_want, cntG, cntE;
    __shared__ int   gidx[128];
    __shared__ float gval[128];
    __shared__ int   eqi[2048];
    __shared__ float vals[MCTX];
    __shared__ int   inds[MCTX];
    __shared__ float pr[MCTX];

    if (t == 0) { sh_prefix = 0u; sh_want = MCTX; cntG = 0; cntE = 0; }

    for (int lvl = 0; lvl < 4; lvl++) {
        int shift = 24 - 8 * lvl;
        for (int i = t; i < 2048; i += 1024) ((int*)hist8)[i] = 0;
        __syncthreads();
        unsigned prefix = sh_prefix;
        unsigned mask = (lvl == 0) ? 0u : (0xFFFFFFFFu << (shift + 8));
        int* hrow = hist8[t & 7];
        for (int c = t; c < NCAND / 4; c += 1024) {
            float4 v = row4[c];
            unsigned k0 = fmapf(v.x), k1 = fmapf(v.y), k2 = fmapf(v.z), k3 = fmapf(v.w);
            if ((k0 & mask) == prefix) atomicAdd(&hrow[(k0 >> shift) & 255], 1);
            if ((k1 & mask) == prefix) atomicAdd(&hrow[(k1 >> shift) & 255], 1);
            if ((k2 & mask) == prefix) atomicAdd(&hrow[(k2 >> shift) & 255], 1);
            if ((k3 & mask) == prefix) atomicAdd(&hrow[(k3 >> shift) & 255], 1);
        }
        __syncthreads();
        if (t < 256) {
            int s = 0;
            for (int g2 = 1; g2 < 8; g2++) s += hist8[g2][t];
            hist8[0][t] += s;
        }
        __syncthreads();
        if (t == 0) {
            int want = sh_want, cum = 0;
            for (int b2 = 255; b2 >= 0; b2--) {
                cum += hist8[0][b2];
                if (cum >= want) {
                    sh_want = want - (cum - hist8[0][b2]);
                    sh_prefix = prefix | ((unsigned)b2 << shift);
                    break;
                }
            }
        }
        __syncthreads();
    }
    unsigned T = sh_prefix;
    for (int c = t; c < NCAND / 4; c += 1024) {
        float4 v = row4[c];
        float vv[4]; vv[0] = v.x; vv[1] = v.y; vv[2] = v.z; vv[3] = v.w;
        for (int e = 0; e < 4; e++) {
            unsigned key = fmapf(vv[e]);
            if (key > T) {
                int p = atomicAdd(&cntG, 1);
                if (p < 128) { gidx[p] = c * 4 + e; gval[p] = vv[e]; }
            } else if (key == T) {
                int p = atomicAdd(&cntE, 1);
                if (p < 2048) eqi[p] = c * 4 + e;
            }
        }
    }
    __syncthreads();
    if (t == 0) {
        int nG = cntG; if (nG > MCTX) nG = MCTX;
        int nE = cntE; if (nE > 2048) nE = 2048;
        int need = MCTX - nG;
        for (int i = 0; i < nG; i++) { inds[i] = gidx[i]; vals[i] = gval[i]; }
        for (int s = 0; s < need; s++) {
            int best = 0x7FFFFFFF, bp = -1;
            for (int e = 0; e < nE; e++) if (eqi[e] < best) { best = eqi[e]; bp = e; }
            if (bp >= 0) { eqi[bp] = 0x7FFFFFFF; inds[nG + s] = best; vals[nG + s] = row[best]; }
            else         { inds[nG + s] = 0;     vals[nG + s] = -3.0e38f; }
        }
        float mx = -3.4e38f;
        for (int i = 0; i < MCTX; i++) if (vals[i] > mx) mx = vals[i];
        float sum = 0.0f;
        for (int i = 0; i < MCTX; i++) { float e = expf(vals[i] - mx); pr[i] = e; sum += e; }
        float inv = 1.0f / sum;
        for (int i = 0; i < MCTX; i++) pr[i] *= inv;
    }
    __syncthreads();
    if (t < MCTX) {
        long long o = (long long)(q0 + blockIdx.x) * MCTX + t;
        out_idx[o] = inds[t];
        out_p[o]   = pr[t];
    }
}

/* ---- D[(b,m),:] = k_b - ck_idx, split output ---- */
extern "C" __global__ __launch_bounds__(256)
void gatherD_sp(const unsigned short* kqh, const unsigned short* kql,
                const unsigned short* kch, const unsigned short* kcl,
                const int* idx, unsigned short* Dh, unsigned short* Dl)
{
    int r = blockIdx.x, t = threadIdx.x;
    int b = r / MCTX;
    int ci = idx[r];
    long long qi = (long long)b * DM + t;
    long long cidx = (long long)ci * DM + t;
    float v = (bfbits(kqh[qi]) + bfbits(kql[qi])) - (bfbits(kch[cidx]) + bfbits(kcl[cidx]));
    unsigned short h = f2bf(v);
    Dh[(long long)r * DM + t] = h;
    Dl[(long long)r * DM + t] = f2bf(v - bfbits(h));
}

extern "C" __global__ __launch_bounds__(256)
void ybar_k(const float* P, const int* idx, const float* y, float* ybar)
{
    __shared__ float sred[256];
    int b = blockIdx.x, t = threadIdx.x;
    float v = 0.0f;
    if (t < MCTX) v = P[(long long)b * MCTX + t] * y[idx[(long long)b * MCTX + t]];
    sred[t] = v; __syncthreads();
    for (int s = 128; s > 0; s >>= 1) { if (t < s) sred[t] += sred[t + s]; __syncthreads(); }
    if (t == 0) ybar[b] = sred[0];
}

extern "C" __global__ __launch_bounds__(512)
void wsum_k(const float* U, const float* P, float* u)
{
    __shared__ float pl[MCTX];
    int b = blockIdx.x, j = threadIdx.x;
    if (j < MCTX) pl[j] = P[(long long)b * MCTX + j];
    __syncthreads();
    const float* Ub = U + (long long)b * MCTX * DH;
    float acc = 0.0f;
    for (int m = 0; m < MCTX; m++) acc += pl[m] * Ub[(long long)m * DH + j];
    u[(long long)b * DH + j] = acc;
}

/* ---- h2 (split, in place) += ybar*Wy + by + bt2 ---- */
extern "C" __global__ __launch_bounds__(256)
void mixprep_sp(unsigned short* h2h, unsigned short* h2l, const float* ybar,
                const float* Wy, const float* by, const float* bt2)
{
    int b = blockIdx.x, d = threadIdx.x;
    long long i = (long long)b * DM + d;
    float v = bfbits(h2h[i]) + bfbits(h2l[i]) + ybar[b] * Wy[d] + by[d] + bt2[d];
    unsigned short h = f2bf(v);
    h2h[i] = h;
    h2l[i] = f2bf(v - bfbits(h));
}

extern "C" __global__ __launch_bounds__(256)
void head_k(const float* X, const float* g, const float* bln, const float* Wh,
            const float* bh, float* out)
{
    __shared__ float sred[256];
    int r = blockIdx.x, t = threadIdx.x;
    float x = X[(long long)r * DM + t];
    sred[t] = x; __syncthreads();
    for (int s = 128; s > 0; s >>= 1) { if (t < s) sred[t] += sred[t + s]; __syncthreads(); }
    float mu = sred[0] * (1.0f / DM); __syncthreads();
    float d = x - mu;
    sred[t] = d * d; __syncthreads();
    for (int s = 128; s > 0; s >>= 1) { if (t < s) sred[t] += sred[t + s]; __syncthreads(); }
    float var = sred[0] * (1.0f / DM); __syncthreads();
    float ln = d * rsqrtf(var + LNEPS) * g[t] + bln[t];
    float rl = (ln > 0.0f) ? ln : 0.0f;
    sred[t] = rl * Wh[t]; __syncthreads();
    for (int s = 128; s > 0; s >>= 1) { if (t < s) sred[t] += sred[t + s]; __syncthreads(); }
    if (t == 0) out[r] = sred[0] + bh[0];
}

#define USP (const unsigned short*)0
#define FP  (const float*)0

extern "C" void kernel_launch(void* const* d_in, const int* in_sizes, int n_in,
                              void* d_out, int out_size, void* d_ws, size_t ws_size,
                              hipStream_t stream)
{
    const float* x_num  = (const float*)d_in[0];
    const float* cand_x = (const float*)d_in[1];
    const float* cand_y = (const float*)d_in[2];
    const float* W_in = (const float*)d_in[4];
    const float* b_in = (const float*)d_in[5];
    const float* We1  = (const float*)d_in[6];
    const float* be1  = (const float*)d_in[7];
    const float* We2  = (const float*)d_in[8];
    const float* be2  = (const float*)d_in[9];
    const float* g_m  = (const float*)d_in[10];
    const float* b_m  = (const float*)d_in[11];
    const float* Ws   = (const float*)d_in[12];
    const float* bs   = (const float*)d_in[13];
    const float* Wy   = (const float*)d_in[14];
    const float* by   = (const float*)d_in[15];
    const float* Wt1  = (const float*)d_in[16];
    const float* Wt2  = (const float*)d_in[17];
    const float* bt2  = (const float*)d_in[18];
    const float* Wp1  = (const float*)d_in[19];
    const float* bp1  = (const float*)d_in[20];
    const float* Wp2  = (const float*)d_in[21];
    const float* bp2  = (const float*)d_in[22];
    const float* g_h  = (const float*)d_in[23];
    const float* b_h  = (const float*)d_in[24];
    const float* Wh   = (const float*)d_in[25];
    const float* bh   = (const float*)d_in[26];
    float* out = (float*)d_out;

    typedef unsigned short us;
    char* p = (char*)d_ws;
    /* weight splits (transposed to [N,K]) */
    us* WinTh = (us*)p; p += 256*96*2;   us* WinTl = (us*)p; p += 256*96*2;
    us* We1Th = (us*)p; p += 512*256*2;  us* We1Tl = (us*)p; p += 512*256*2;
    us* We2Th = (us*)p; p += 256*512*2;  us* We2Tl = (us*)p; p += 256*512*2;
    us* WsTh  = (us*)p; p += 256*256*2;  us* WsTl  = (us*)p; p += 256*256*2;
    us* Wt1Th = (us*)p; p += 512*256*2;  us* Wt1Tl = (us*)p; p += 512*256*2;
    us* Wt2Th = (us*)p; p += 256*512*2;  us* Wt2Tl = (us*)p; p += 256*512*2;
    us* Wp1Th = (us*)p; p += 512*256*2;  us* Wp1Tl = (us*)p; p += 512*256*2;
    us* Wp2Th = (us*)p; p += 256*512*2;  us* Wp2Tl = (us*)p; p += 256*512*2;
    /* activation splits */
    us* XNh = (us*)p;  p += (long long)NB*DNUM*2;     us* XNl = (us*)p;  p += (long long)NB*DNUM*2;
    us* CXh = (us*)p;  p += (long long)NCAND*DNUM*2;  us* CXl = (us*)p;  p += (long long)NCAND*DNUM*2;
    us* HQ1h = (us*)p; p += (long long)NB*DM*2;       us* HQ1l = (us*)p; p += (long long)NB*DM*2;
    us* TQh  = (us*)p; p += (long long)NB*DH*2;       us* TQl  = (us*)p; p += (long long)NB*DH*2;
    us* HQ2h = (us*)p; p += (long long)NB*DM*2;       us* HQ2l = (us*)p; p += (long long)NB*DM*2;
    us* LNQh = (us*)p; p += (long long)NB*DM*2;       us* LNQl = (us*)p; p += (long long)NB*DM*2;
    us* KQh  = (us*)p; p += (long long)NB*DM*2;       us* KQl  = (us*)p; p += (long long)NB*DM*2;
    us* XQh  = (us*)p; p += (long long)NB*DM*2;       us* XQl  = (us*)p; p += (long long)NB*DM*2;
    us* UQvh = (us*)p; p += (long long)NB*DH*2;       us* UQvl = (us*)p; p += (long long)NB*DH*2;
    float* UQv  = (float*)p; p += (long long)NB*DH*4;
    float* XQ2f = (float*)p; p += (long long)NB*DM*4;
    float* YB   = (float*)p; p += (long long)NB*4;
    int*   IDX  = (int*)p;   p += (long long)NB*MCTX*4;
    float* PRB  = (float*)p; p += (long long)NB*MCTX*4;
    us* KCh = (us*)p; p += (long long)NCAND*DM*2;     us* KCl = (us*)p; p += (long long)NCAND*DM*2;
    float* SC = (float*)p; p += (long long)NCAND*4;
    /* phase-overlaid arena */
    size_t used = (size_t)(p - (char*)d_ws);
    long long avail = (ws_size > used + 4096) ? (long long)(ws_size - used - 4096) : 0;
    int EC = 6250;
    if      (avail >= 204800000LL) EC = 50000;
    else if (avail >= 102400000LL) EC = 25000;
    else if (avail >=  51200000LL) EC = 12500;
    int QS = 64;
    if      (avail >= 102400000LL) QS = 256;
    else if (avail >=  51200000LL) QS = 128;
    int VC = 64;
    if      (avail >= 150994944LL) VC = 512;
    else if (avail >=  75497472LL) VC = 256;
    else if (avail >=  37748736LL) VC = 128;
    char* AR = p;
    us* Hch = (us*)AR;                                us* Hcl = Hch + (long long)EC*DM;
    us* Tch = (us*)(AR + (long long)EC*DM*4);         us* Tcl = Tch + (long long)EC*DH;
    us* H2ch = (us*)(AR + (long long)EC*(DM+DH)*4);   us* H2cl = H2ch + (long long)EC*DM;
    us* LNch = Hch; us* LNcl = Hcl;                   /* Hc dead after We2 gemm */
    float* Sb = (float*)AR;
    us* Dbh = (us*)AR;                                us* Dbl = Dbh + (long long)VC*MCTX*DM;
    float* Ub = (float*)(AR + (long long)VC*MCTX*DM*4);

    dim3 blk(256);

    /* ---- one-time splits ---- */
    splitT_k<<<dim3((DNUM*DM+255)/256), blk, 0, stream>>>(W_in, WinTh, WinTl, DNUM, DM);
    splitT_k<<<dim3((DM*DH+255)/256), blk, 0, stream>>>(We1, We1Th, We1Tl, DM, DH);
    splitT_k<<<dim3((DH*DM+255)/256), blk, 0, stream>>>(We2, We2Th, We2Tl, DH, DM);
    splitT_k<<<dim3((DM*DM+255)/256), blk, 0, stream>>>(Ws,  WsTh,  WsTl,  DM, DM);
    splitT_k<<<dim3((DM*DH+255)/256), blk, 0, stream>>>(Wt1, Wt1Th, Wt1Tl, DM, DH);
    splitT_k<<<dim3((DH*DM+255)/256), blk, 0, stream>>>(Wt2, Wt2Th, Wt2Tl, DH, DM);
    splitT_k<<<dim3((DM*DH+255)/256), blk, 0, stream>>>(Wp1, Wp1Th, Wp1Tl, DM, DH);
    splitT_k<<<dim3((DH*DM+255)/256), blk, 0, stream>>>(Wp2, Wp2Th, Wp2Tl, DH, DM);
    split_k<<<dim3((NB*DNUM+255)/256), blk, 0, stream>>>(x_num, XNh, XNl, (long long)NB*DNUM);
    split_k<<<dim3((NCAND*DNUM+255)/256), blk, 0, stream>>>(cand_x, CXh, CXl, (long long)NCAND*DNUM);

    /* ---- query encode ---- */
    gemm_sp<<<dim3(DM/128, NB/128), blk, 0, stream>>>(XNh, XNl, WinTh, WinTl,
        (float*)0, HQ1h, HQ1l, b_in, USP, USP, FP, NB, DM, DNUM, 0, 0);
    gemm_sp<<<dim3(DH/128, NB/128), blk, 0, stream>>>(HQ1h, HQ1l, We1Th, We1Tl,
        (float*)0, TQh, TQl, be1, USP, USP, FP, NB, DH, DM, 1, 0);
    gemm_sp<<<dim3(DM/128, NB/128), blk, 0, stream>>>(TQh, TQl, We2Th, We2Tl,
        (float*)0, HQ2h, HQ2l, be2, HQ1h, HQ1l, FP, NB, DM, DH, 0, 0);
    ln_sp<<<dim3(NB), blk, 0, stream>>>(HQ2h, HQ2l, LNQh, LNQl, g_m, b_m);
    gemm_sp<<<dim3(DM/128, NB/128), blk, 0, stream>>>(LNQh, LNQl, WsTh, WsTl,
        (float*)0, KQh, KQl, bs, USP, USP, FP, NB, DM, DM, 0, 0);

    /* ---- candidate encode ---- */
    for (int c0 = 0; c0 < NCAND; c0 += EC) {
        int gy = (EC + 127) / 128;
        gemm_sp<<<dim3(DM/128, gy), blk, 0, stream>>>(CXh + (long long)c0*DNUM, CXl + (long long)c0*DNUM,
            WinTh, WinTl, (float*)0, Hch, Hcl, b_in, USP, USP, FP, EC, DM, DNUM, 0, 0);
        gemm_sp<<<dim3(DH/128, gy), blk, 0, stream>>>(Hch, Hcl, We1Th, We1Tl,
            (float*)0, Tch, Tcl, be1, USP, USP, FP, EC, DH, DM, 1, 0);
        gemm_sp<<<dim3(DM/128, gy), blk, 0, stream>>>(Tch, Tcl, We2Th, We2Tl,
            (float*)0, H2ch, H2cl, be2, Hch, Hcl, FP, EC, DM, DH, 0, 0);
        ln_sp<<<dim3(EC), blk, 0, stream>>>(H2ch, H2cl, LNch, LNcl, g_m, b_m);
        gemm_sp<<<dim3(DM/128, gy), blk, 0, stream>>>(LNch, LNcl, WsTh, WsTl,
            (float*)0, KCh + (long long)c0*DM, KCl + (long long)c0*DM, bs, USP, USP, FP, EC, DM, DM, 0, 0);
    }
    snorm_sp<<<dim3(NCAND), blk, 0, stream>>>(KCh, KCl, SC);

    /* ---- sim (2*k.ck - ||ck||^2) + exact top-96 ---- */
    for (int q0 = 0; q0 < NB; q0 += QS) {
        gemm_sp<<<dim3((NCAND+127)/128, QS/128), blk, 0, stream>>>(
            KQh + (long long)q0*DM, KQl + (long long)q0*DM, KCh, KCl,
            Sb, (us*)0, (us*)0, FP, USP, USP, SC, QS, NCAND, DM, 0, 1);
        topk_k<<<dim3(QS), dim3(1024), 0, stream>>>(Sb, q0, IDX, PRB);
    }

    /* ---- value aggregation ---- */
    ybar_k<<<dim3(NB), blk, 0, stream>>>(PRB, IDX, cand_y, YB);
    for (int v0 = 0; v0 < NB; v0 += VC) {
        gatherD_sp<<<dim3(VC*MCTX), blk, 0, stream>>>(
            KQh + (long long)v0*DM, KQl + (long long)v0*DM, KCh, KCl,
            IDX + (long long)v0*MCTX, Dbh, Dbl);
        gemm_sp<<<dim3(DH/128, (VC*MCTX)/128), blk, 0, stream>>>(Dbh, Dbl, Wt1Th, Wt1Tl,
            Ub, (us*)0, (us*)0, FP, USP, USP, FP, VC*MCTX, DH, DM, 1, 0);
        wsum_k<<<dim3(VC), dim3(512), 0, stream>>>(Ub, PRB + (long long)v0*MCTX, UQv + (long long)v0*DH);
    }
    split_k<<<dim3((NB*DH+255)/256), blk, 0, stream>>>(UQv, UQvh, UQvl, (long long)NB*DH);
    mixprep_sp<<<dim3(NB), blk, 0, stream>>>(HQ2h, HQ2l, YB, Wy, by, bt2);
    gemm_sp<<<dim3(DM/128, NB/128), blk, 0, stream>>>(UQvh, UQvl, Wt2Th, Wt2Tl,
        (float*)0, XQh, XQl, FP, HQ2h, HQ2l, FP, NB, DM, DH, 0, 0);

    /* ---- predictor block + head ---- */
    gemm_sp<<<dim3(DH/128, NB/128), blk, 0, stream>>>(XQh, XQl, Wp1Th, Wp1Tl,
        (float*)0, TQh, TQl, bp1, USP, USP, FP, NB, DH, DM, 1, 0);
    gemm_sp<<<dim3(DM/128, NB/128), blk, 0, stream>>>(TQh, TQl, Wp2Th, Wp2Tl,
        XQ2f, (us*)0, (us*)0, bp2, XQh, XQl, FP, NB, DM, DH, 0, 0);
    head_k<<<dim3(NB), blk, 0, stream>>>(XQ2f, g_h, b_h, Wh, bh, out);
}

// Round 7
// 4368.946 us; speedup vs baseline: 3.2603x; 1.1032x over previous
//
#include <hip/hip_runtime.h>
#include <stdint.h>

#define NCAND 100000
#define NB    1024
#define DNUM  96
#define DM    256
#define DH    512
#define MCTX  96
#define LNEPS 1e-5f

typedef __bf16 bf16x8 __attribute__((ext_vector_type(8)));
typedef float  f32x4  __attribute__((ext_vector_type(4)));
typedef unsigned short u16x8 __attribute__((ext_vector_type(8)));
typedef unsigned short us;

__device__ __forceinline__ us f2bf(float x)
{
    unsigned u = __float_as_uint(x);
    unsigned r = u + 0x7FFFu + ((u >> 16) & 1u);   /* RNE */
    return (us)(r >> 16);
}
__device__ __forceinline__ float bfbits(us h)
{
    return __uint_as_float(((unsigned)h) << 16);
}

extern "C" __global__ __launch_bounds__(256)
void fill_out_k(float* out, int n)
{
    int i = blockIdx.x * 256 + threadIdx.x;
    if (i < n) out[i] = 777.0f;
}

/* ---- split f32 -> (hi,lo) bf16, same layout ---- */
extern "C" __global__ __launch_bounds__(256)
void split_k(const float* X, us* Xh, us* Xl, long long n)
{
    long long i = (long long)blockIdx.x * 256 + threadIdx.x;
    if (i < n) {
        float x = X[i];
        us h = f2bf(x);
        Xh[i] = h;
        Xl[i] = f2bf(x - bfbits(h));
    }
}

/* ---- split + transpose: W[Kd,Nd] -> T[Nd,Kd] ---- */
extern "C" __global__ __launch_bounds__(256)
void splitT_k(const float* W, us* Th, us* Tl, int Kd, int Nd)
{
    int i = blockIdx.x * 256 + threadIdx.x;
    if (i < Kd * Nd) {
        int k = i / Nd, n2 = i - k * Nd;
        float x = W[i];
        us h = f2bf(x);
        Th[(long long)n2 * Kd + k] = h;
        Tl[(long long)n2 * Kd + k] = f2bf(x - bfbits(h));
    }
}

/* =====================================================================
   Full-N split-bf16 MFMA GEMM. M-tile=64 (blockIdx.x), N = NCOLS (256/512),
   A[M,K] read ONCE; B[N,K] split (weights, L2-resident). 4 waves split N.
   acc = Ah*Bh + Ah*Bl + Al*Bh (f32 accum, rel err ~1e-4).
   Modes: bias(f32), resid(split), relu; outputs f32 / split / plain-bf16;
   fused LayerNorm (pass1 stats, pass2 write); fused row-sumsq (snOut);
   gather-A mode (A row = kq[b] - kc[idx]); sim mode (v=2*acc - colb[row],
   LDS-transposed coalesced write to simT[q][cand], K%32==0, M%16==0).
   ===================================================================== */
#define GEMM_BODY(NCOLS, NJW) \
{ \
    __shared__ us Ahs[64][40]; \
    __shared__ us Als[64][40]; \
    __shared__ us Bhs[NCOLS][40]; \
    __shared__ us Bls[NCOLS][40]; \
    __shared__ float red1[256]; \
    __shared__ float red2[256]; \
    __shared__ float mu_s[64]; \
    __shared__ float rs_s[64]; \
    const int N = NCOLS; \
    int t = threadIdx.x, wave = t >> 6, lane = t & 63; \
    int lm = lane & 15, lk = (lane >> 4) * 8, rb = (lane >> 4) * 4; \
    int m0 = blockIdx.x * 64; \
    f32x4 acc[4][NJW]; \
    _Pragma("unroll") \
    for (int i = 0; i < 4; i++) \
        _Pragma("unroll") \
        for (int j = 0; j < NJW; j++) \
            for (int e = 0; e < 4; e++) acc[i][j][e] = 0.0f; \
    int ar = t >> 2, aseg = (t & 3) * 8; \
    int grow = m0 + ar; \
    int gb = 0, gc = 0; \
    if (gidx && grow < M) { gb = grow / MCTX; gc = gidx[grow]; } \
    for (int k0 = 0; k0 < K; k0 += 32) { \
        u16x8 ah8 = {0,0,0,0,0,0,0,0}, al8 = ah8; \
        if (grow < M) { \
            if (!gidx) { \
                ah8 = *(const u16x8*)(Ah + (long long)grow * K + k0 + aseg); \
                al8 = *(const u16x8*)(Al + (long long)grow * K + k0 + aseg); \
            } else { \
                u16x8 qh = *(const u16x8*)(Gqh + (long long)gb * DM + k0 + aseg); \
                u16x8 ql = *(const u16x8*)(Gql + (long long)gb * DM + k0 + aseg); \
                u16x8 ch = *(const u16x8*)(Gch + (long long)gc * DM + k0 + aseg); \
                u16x8 cl = *(const u16x8*)(Gcl + (long long)gc * DM + k0 + aseg); \
                _Pragma("unroll") \
                for (int e = 0; e < 8; e++) { \
                    float v = bfbits(qh[e]) + bfbits(ql[e]) - bfbits(ch[e]) - bfbits(cl[e]); \
                    us h = f2bf(v); ah8[e] = h; al8[e] = f2bf(v - bfbits(h)); \
                } \
            } \
        } \
        u16x8 bh8[NJW], bl8[NJW]; \
        _Pragma("unroll") \
        for (int r = 0; r < NJW; r++) { \
            int idx = r * 256 + t; int bn = idx >> 2; int bseg = (idx & 3) * 8; \
            bh8[r] = *(const u16x8*)(Bh + (long long)bn * K + k0 + bseg); \
            bl8[r] = *(const u16x8*)(Bl + (long long)bn * K + k0 + bseg); \
        } \
        __syncthreads(); \
        *(u16x8*)&Ahs[ar][aseg] = ah8; \
        *(u16x8*)&Als[ar][aseg] = al8; \
        _Pragma("unroll") \
        for (int r = 0; r < NJW; r++) { \
            int idx = r * 256 + t; int bn = idx >> 2; int bseg = (idx & 3) * 8; \
            *(u16x8*)&Bhs[bn][bseg] = bh8[r]; \
            *(u16x8*)&Bls[bn][bseg] = bl8[r]; \
        } \
        __syncthreads(); \
        bf16x8 fah[4], fal[4]; \
        _Pragma("unroll") \
        for (int i = 0; i < 4; i++) { \
            fah[i] = *(const bf16x8*)&Ahs[i * 16 + lm][lk]; \
            fal[i] = *(const bf16x8*)&Als[i * 16 + lm][lk]; \
        } \
        _Pragma("unroll") \
        for (int j = 0; j < NJW; j++) { \
            bf16x8 fbh = *(const bf16x8*)&Bhs[wave * (NCOLS / 4) + j * 16 + lm][lk]; \
            bf16x8 fbl = *(const bf16x8*)&Bls[wave * (NCOLS / 4) + j * 16 + lm][lk]; \
            _Pragma("unroll") \
            for (int i = 0; i < 4; i++) { \
                acc[i][j] = __builtin_amdgcn_mfma_f32_16x16x32_bf16(fah[i], fbh, acc[i][j], 0, 0, 0); \
                acc[i][j] = __builtin_amdgcn_mfma_f32_16x16x32_bf16(fah[i], fbl, acc[i][j], 0, 0, 0); \
                acc[i][j] = __builtin_amdgcn_mfma_f32_16x16x32_bf16(fal[i], fbh, acc[i][j], 0, 0, 0); \
            } \
        } \
    } \
    if (simT) { \
        __syncthreads(); \
        float* tb = ((float*)&Bhs[0][0]) + wave * ((NCOLS / 4) * 16); \
        for (int i = 0; i < 4; i++) { \
            int cb = m0 + i * 16; \
            if (cb >= M) break; \
            _Pragma("unroll") \
            for (int j = 0; j < NJW; j++) \
                for (int e = 0; e < 4; e++) \
                    tb[(j * 16 + lm) * 16 + rb + e] = 2.0f * acc[i][j][e] - colb[cb + rb + e]; \
            for (int q2 = 0; q2 < NCOLS / 256; q2++) { \
                int q = q2 * 64 + lane; \
                float* src = tb + q * 16; \
                float* dst = simT + (long long)(wave * (NCOLS / 4) + q) * NCAND + cb; \
                f32x4 v0 = *(f32x4*)src; f32x4 v1 = *(f32x4*)(src + 4); \
                f32x4 v2 = *(f32x4*)(src + 8); f32x4 v3 = *(f32x4*)(src + 12); \
                *(f32x4*)dst = v0; *(f32x4*)(dst + 4) = v1; \
                *(f32x4*)(dst + 8) = v2; *(f32x4*)(dst + 12) = v3; \
            } \
        } \
        return; \
    } \
    int dored = (lng != (const float*)0) || (snOut != (float*)0); \
    for (int i = 0; i < 4; i++) \
    for (int e = 0; e < 4; e++) { \
        int lr = i * 16 + rb + e; \
        int row = m0 + lr; \
        float s1 = 0.0f, s2 = 0.0f; \
        _Pragma("unroll") \
        for (int j = 0; j < NJW; j++) { \
            int col = wave * (NCOLS / 4) + j * 16 + lm; \
            float v = acc[i][j][e]; \
            if (bias) v += bias[col]; \
            long long oix = (long long)row * N + col; \
            if (Rh && row < M) v += bfbits(Rh[oix]) + bfbits(Rl[oix]); \
            if (dorelu && v < 0.0f) v = 0.0f; \
            if (row < M) { \
                if (outF) outF[oix] = v; \
                if (outB16) outB16[oix] = f2bf(v); \
                if (outH) { us h = f2bf(v); outH[oix] = h; outL[oix] = f2bf(v - bfbits(h)); } \
            } \
            s1 += v; s2 += v * v; \
        } \
        if (dored) { \
            for (int o = 1; o < 16; o <<= 1) { s1 += __shfl_xor(s1, o, 64); s2 += __shfl_xor(s2, o, 64); } \
            if (lm == 0) { red1[lr * 4 + wave] = s1; red2[lr * 4 + wave] = s2; } \
        } \
    } \
    if (dored) { \
        __syncthreads(); \
        if (t < 64) { \
            float a = red1[t*4] + red1[t*4+1] + red1[t*4+2] + red1[t*4+3]; \
            float b2 = red2[t*4] + red2[t*4+1] + red2[t*4+2] + red2[t*4+3]; \
            if (lng) { \
                float mu = a * (1.0f / N); \
                float var = b2 * (1.0f / N) - mu * mu; \
                mu_s[t] = mu; rs_s[t] = rsqrtf(var + LNEPS); \
            } \
            if (snOut && (m0 + t) < M) snOut[m0 + t] = b2; \
        } \
        __syncthreads(); \
        if (lng) { \
            for (int i = 0; i < 4; i++) \
            for (int e = 0; e < 4; e++) { \
                int lr = i * 16 + rb + e; \
                int row = m0 + lr; \
                if (row >= M) continue; \
                float mu = mu_s[lr], rs = rs_s[lr]; \
                _Pragma("unroll") \
                for (int j = 0; j < NJW; j++) { \
                    int col = wave * (NCOLS / 4) + j * 16 + lm; \
                    float v = acc[i][j][e]; \
                    if (bias) v += bias[col]; \
                    long long oix = (long long)row * N + col; \
                    if (Rh) v += bfbits(Rh[oix]) + bfbits(Rl[oix]); \
                    if (dorelu && v < 0.0f) v = 0.0f; \
                    float y = (v - mu) * rs * lng[col] + lnb[col]; \
                    us h = f2bf(y); lnH[oix] = h; lnL[oix] = f2bf(y - bfbits(h)); \
                } \
            } \
        } \
    } \
}

#define GEMM_ARGS \
    const us* Ah, const us* Al, const us* Bh, const us* Bl, \
    float* outF, us* outH, us* outL, us* outB16, \
    const float* bias, const us* Rh, const us* Rl, int dorelu, \
    const float* lng, const float* lnb, us* lnH, us* lnL, \
    float* snOut, \
    const us* Gqh, const us* Gql, const us* Gch, const us* Gcl, const int* gidx, \
    float* simT, const float* colb, \
    int M, int K

extern "C" __global__ __launch_bounds__(256)
void gemm256(GEMM_ARGS) GEMM_BODY(256, 4)

extern "C" __global__ __launch_bounds__(256)
void gemm512(GEMM_ARGS) GEMM_BODY(512, 8)

__device__ unsigned fmapf(float f)
{
    unsigned u = __float_as_uint(f);
    return u ^ (unsigned)(((int)u >> 31) | (int)0x80000000);
}

/* exact top-96 (radix select 4x8-bit, ties -> smallest index) + softmax */
extern "C" __global__ __launch_bounds__(1024)
void topk_k(const float* S, int q0, int* out_idx, float* out_p)
{
    int t = threadIdx.x;
    const float* row = S + (long long)blockIdx.x * NCAND;
    const float4* row4 = (const float4*)row;
    __shared__ int hist8[8][256];
    __shared__ unsigned sh_prefix;
    __shared__ int sh_want, cntG, cntE;
    __shared__ int   gidx[128];
    __shared__ float gval[128];
    __shared__ int   eqi[2048];
    __shared__ float vals[MCTX];
    __shared__ int   inds[MCTX];
    __shared__ float pr[MCTX];

    if (t == 0) { sh_prefix = 0u; sh_want = MCTX; cntG = 0; cntE = 0; }

    for (int lvl = 0; lvl < 4; lvl++) {
        int shift = 24 - 8 * lvl;
        for (int i = t; i < 2048; i += 1024) ((int*)hist8)[i] = 0;
        __syncthreads();
        unsigned prefix = sh_prefix;
        unsigned mask = (lvl == 0) ? 0u : (0xFFFFFFFFu << (shift + 8));
        int* hrow = hist8[t & 7];
        for (int c = t; c < NCAND / 4; c += 1024) {
            float4 v = row4[c];
            unsigned k0 = fmapf(v.x), k1 = fmapf(v.y), k2 = fmapf(v.z), k3 = fmapf(v.w);
            if ((k0 & mask) == prefix) atomicAdd(&hrow[(k0 >> shift) & 255], 1);
            if ((k1 & mask) == prefix) atomicAdd(&hrow[(k1 >> shift) & 255], 1);
            if ((k2 & mask) == prefix) atomicAdd(&hrow[(k2 >> shift) & 255], 1);
            if ((k3 & mask) == prefix) atomicAdd(&hrow[(k3 >> shift) & 255], 1);
        }
        __syncthreads();
        if (t < 256) {
            int s = 0;
            for (int g2 = 1; g2 < 8; g2++) s += hist8[g2][t];
            hist8[0][t] += s;
        }
        __syncthreads();
        if (t == 0) {
            int want = sh_want, cum = 0;
            for (int b2 = 255; b2 >= 0; b2--) {
                cum += hist8[0][b2];
                if (cum >= want) {
                    sh_want = want - (cum - hist8[0][b2]);
                    sh_prefix = prefix | ((unsigned)b2 << shift);
                    break;
                }
            }
        }
        __syncthreads();
    }
    unsigned T = sh_prefix;
    for (int c = t; c < NCAND / 4; c += 1024) {
        float4 v = row4[c];
        float vv[4]; vv[0] = v.x; vv[1] = v.y; vv[2] = v.z; vv[3] = v.w;
        for (int e = 0; e < 4; e++) {
            unsigned key = fmapf(vv[e]);
            if (key > T) {
                int p = atomicAdd(&cntG, 1);
                if (p < 128) { gidx[p] = c * 4 + e; gval[p] = vv[e]; }
            } else if (key == T) {
                int p = atomicAdd(&cntE, 1);
                if (p < 2048) eqi[p] = c * 4 + e;
            }
        }
    }
    __syncthreads();
    if (t == 0) {
        int nG = cntG; if (nG > MCTX) nG = MCTX;
        int nE = cntE; if (nE > 2048) nE = 2048;
        int need = MCTX - nG;
        for (int i = 0; i < nG; i++) { inds[i] = gidx[i]; vals[i] = gval[i]; }
        for (int s = 0; s < need; s++) {
            int best = 0x7FFFFFFF, bp = -1;
            for (int e = 0; e < nE; e++) if (eqi[e] < best) { best = eqi[e]; bp = e; }
            if (bp >= 0) { eqi[bp] = 0x7FFFFFFF; inds[nG + s] = best; vals[nG + s] = row[best]; }
            else         { inds[nG + s] = 0;     vals[nG + s] = -3.0e38f; }
        }
        float mx = -3.4e38f;
        for (int i = 0; i < MCTX; i++) if (vals[i] > mx) mx = vals[i];
        float sum = 0.0f;
        for (int i = 0; i < MCTX; i++) { float e = expf(vals[i] - mx); pr[i] = e; sum += e; }
        float inv = 1.0f / sum;
        for (int i = 0; i < MCTX; i++) pr[i] *= inv;
    }
    __syncthreads();
    if (t < MCTX) {
        long long o = (long long)(q0 + blockIdx.x) * MCTX + t;
        out_idx[o] = inds[t];
        out_p[o]   = pr[t];
    }
}

extern "C" __global__ __launch_bounds__(256)
void ybar_k(const float* P, const int* idx, const float* y, float* ybar)
{
    __shared__ float sred[256];
    int b = blockIdx.x, t = threadIdx.x;
    float v = 0.0f;
    if (t < MCTX) v = P[(long long)b * MCTX + t] * y[idx[(long long)b * MCTX + t]];
    sred[t] = v; __syncthreads();
    for (int s = 128; s > 0; s >>= 1) { if (t < s) sred[t] += sred[t + s]; __syncthreads(); }
    if (t == 0) ybar[b] = sred[0];
}

/* u[b,j] = sum_m p_m * U[(b,m),j] ; U is plain bf16 */
extern "C" __global__ __launch_bounds__(512)
void wsum_k(const us* U, const float* P, float* u)
{
    __shared__ float pl[MCTX];
    int b = blockIdx.x, j = threadIdx.x;
    if (j < MCTX) pl[j] = P[(long long)b * MCTX + j];
    __syncthreads();
    const us* Ub = U + (long long)b * MCTX * DH;
    float acc = 0.0f;
    for (int m = 0; m < MCTX; m++) acc += pl[m] * bfbits(Ub[(long long)m * DH + j]);
    u[(long long)b * DH + j] = acc;
}

/* h2 (split, in place) += ybar*Wy + by + bt2 */
extern "C" __global__ __launch_bounds__(256)
void mixprep_sp(us* h2h, us* h2l, const float* ybar,
                const float* Wy, const float* by, const float* bt2)
{
    int b = blockIdx.x, d = threadIdx.x;
    long long i = (long long)b * DM + d;
    float v = bfbits(h2h[i]) + bfbits(h2l[i]) + ybar[b] * Wy[d] + by[d] + bt2[d];
    us h = f2bf(v);
    h2h[i] = h;
    h2l[i] = f2bf(v - bfbits(h));
}

extern "C" __global__ __launch_bounds__(256)
void head_k(const float* X, const float* g, const float* bln, const float* Wh,
            const float* bh, float* out)
{
    __shared__ float sred[256];
    int r = blockIdx.x, t = threadIdx.x;
    float x = X[(long long)r * DM + t];
    sred[t] = x; __syncthreads();
    for (int s = 128; s > 0; s >>= 1) { if (t < s) sred[t] += sred[t + s]; __syncthreads(); }
    float mu = sred[0] * (1.0f / DM); __syncthreads();
    float d = x - mu;
    sred[t] = d * d; __syncthreads();
    for (int s = 128; s > 0; s >>= 1) { if (t < s) sred[t] += sred[t + s]; __syncthreads(); }
    float var = sred[0] * (1.0f / DM); __syncthreads();
    float ln = d * rsqrtf(var + LNEPS) * g[t] + bln[t];
    float rl = (ln > 0.0f) ? ln : 0.0f;
    sred[t] = rl * Wh[t]; __syncthreads();
    for (int s = 128; s > 0; s >>= 1) { if (t < s) sred[t] += sred[t + s]; __syncthreads(); }
    if (t == 0) out[r] = sred[0] + bh[0];
}

#define ZU (us*)0
#define ZCU (const us*)0
#define ZF (float*)0
#define ZCF (const float*)0
#define ZI (const int*)0

extern "C" void kernel_launch(void* const* d_in, const int* in_sizes, int n_in,
                              void* d_out, int out_size, void* d_ws, size_t ws_size,
                              hipStream_t stream)
{
    const float* x_num  = (const float*)d_in[0];
    const float* cand_x = (const float*)d_in[1];
    const float* cand_y = (const float*)d_in[2];
    const float* W_in = (const float*)d_in[4];
    const float* b_in = (const float*)d_in[5];
    const float* We1  = (const float*)d_in[6];
    const float* be1  = (const float*)d_in[7];
    const float* We2  = (const float*)d_in[8];
    const float* be2  = (const float*)d_in[9];
    const float* g_m  = (const float*)d_in[10];
    const float* b_m  = (const float*)d_in[11];
    const float* Ws   = (const float*)d_in[12];
    const float* bs   = (const float*)d_in[13];
    const float* Wy   = (const float*)d_in[14];
    const float* by   = (const float*)d_in[15];
    const float* Wt1  = (const float*)d_in[16];
    const float* Wt2  = (const float*)d_in[17];
    const float* bt2  = (const float*)d_in[18];
    const float* Wp1  = (const float*)d_in[19];
    const float* bp1  = (const float*)d_in[20];
    const float* Wp2  = (const float*)d_in[21];
    const float* bp2  = (const float*)d_in[22];
    const float* g_h  = (const float*)d_in[23];
    const float* b_h  = (const float*)d_in[24];
    const float* Wh   = (const float*)d_in[25];
    const float* bh   = (const float*)d_in[26];
    float* out = (float*)d_out;

    char* p = (char*)d_ws;
    /* weight splits (transposed to [N,K]) */
    us* WinTh = (us*)p; p += 256*96*2;   us* WinTl = (us*)p; p += 256*96*2;
    us* We1Th = (us*)p; p += 512*256*2;  us* We1Tl = (us*)p; p += 512*256*2;
    us* We2Th = (us*)p; p += 256*512*2;  us* We2Tl = (us*)p; p += 256*512*2;
    us* WsTh  = (us*)p; p += 256*256*2;  us* WsTl  = (us*)p; p += 256*256*2;
    us* Wt1Th = (us*)p; p += 512*256*2;  us* Wt1Tl = (us*)p; p += 512*256*2;
    us* Wt2Th = (us*)p; p += 256*512*2;  us* Wt2Tl = (us*)p; p += 256*512*2;
    us* Wp1Th = (us*)p; p += 512*256*2;  us* Wp1Tl = (us*)p; p += 512*256*2;
    us* Wp2Th = (us*)p; p += 256*512*2;  us* Wp2Tl = (us*)p; p += 256*512*2;
    /* activation splits */
    us* XNh  = (us*)p; p += (long long)NB*DNUM*2;     us* XNl  = (us*)p; p += (long long)NB*DNUM*2;
    us* CXh  = (us*)p; p += (long long)NCAND*DNUM*2;  us* CXl  = (us*)p; p += (long long)NCAND*DNUM*2;
    us* HQ1h = (us*)p; p += (long long)NB*DM*2;       us* HQ1l = (us*)p; p += (long long)NB*DM*2;
    us* TQh  = (us*)p; p += (long long)NB*DH*2;       us* TQl  = (us*)p; p += (long long)NB*DH*2;
    us* HQ2h = (us*)p; p += (long long)NB*DM*2;       us* HQ2l = (us*)p; p += (long long)NB*DM*2;
    us* LNQh = (us*)p; p += (long long)NB*DM*2;       us* LNQl = (us*)p; p += (long long)NB*DM*2;
    us* KQh  = (us*)p; p += (long long)NB*DM*2;       us* KQl  = (us*)p; p += (long long)NB*DM*2;
    us* XQh  = (us*)p; p += (long long)NB*DM*2;       us* XQl  = (us*)p; p += (long long)NB*DM*2;
    us* UQvh = (us*)p; p += (long long)NB*DH*2;       us* UQvl = (us*)p; p += (long long)NB*DH*2;
    float* UQv  = (float*)p; p += (long long)NB*DH*4;
    float* XQ2f = (float*)p; p += (long long)NB*DM*4;
    float* YB   = (float*)p; p += (long long)NB*4;
    int*   IDX  = (int*)p;   p += (long long)NB*MCTX*4;
    float* PRB  = (float*)p; p += (long long)NB*MCTX*4;
    us* KCh = (us*)p; p += (long long)NCAND*DM*2;     us* KCl = (us*)p; p += (long long)NCAND*DM*2;
    float* SC = (float*)p; p += (long long)NCAND*4;

    size_t used = (size_t)(p - (char*)d_ws);
    long long avail = (ws_size > used + 4096) ? (long long)(ws_size - used - 4096) : 0;
    int EC = 6250;
    if      (avail >= 204800000LL) EC = 50000;
    else if (avail >= 102400000LL) EC = 25000;
    else if (avail >=  51200000LL) EC = 12500;
    int QS = (avail >= 204800000LL) ? 512 : 256;       /* sim queries / dispatch */
    int VC = 256;
    if      (avail >= 100663296LL) VC = 1024;
    else if (avail >=  50331648LL) VC = 512;

    char* AR = p;  /* phase-overlaid arena (phases stream-sequential) */
    us* Hch  = (us*)AR;                                us* Hcl  = Hch + (long long)EC*DM;
    us* Tch  = (us*)(AR + (long long)EC*DM*4);         us* Tcl  = Tch + (long long)EC*DH;
    us* LNch = (us*)(AR + (long long)EC*(DM+DH)*4);    us* LNcl = LNch + (long long)EC*DM;
    float* Sb = (float*)AR;
    us* Ub = (us*)AR;

    dim3 blk(256);

    fill_out_k<<<dim3((NB + 255) / 256), blk, 0, stream>>>(out, NB);

    /* ---- one-time splits ---- */
    splitT_k<<<dim3((DNUM*DM+255)/256), blk, 0, stream>>>(W_in, WinTh, WinTl, DNUM, DM);
    splitT_k<<<dim3((DM*DH+255)/256), blk, 0, stream>>>(We1, We1Th, We1Tl, DM, DH);
    splitT_k<<<dim3((DH*DM+255)/256), blk, 0, stream>>>(We2, We2Th, We2Tl, DH, DM);
    splitT_k<<<dim3((DM*DM+255)/256), blk, 0, stream>>>(Ws,  WsTh,  WsTl,  DM, DM);
    splitT_k<<<dim3((DM*DH+255)/256), blk, 0, stream>>>(Wt1, Wt1Th, Wt1Tl, DM, DH);
    splitT_k<<<dim3((DH*DM+255)/256), blk, 0, stream>>>(Wt2, Wt2Th, Wt2Tl, DH, DM);
    splitT_k<<<dim3((DM*DH+255)/256), blk, 0, stream>>>(Wp1, Wp1Th, Wp1Tl, DM, DH);
    splitT_k<<<dim3((DH*DM+255)/256), blk, 0, stream>>>(Wp2, Wp2Th, Wp2Tl, DH, DM);
    split_k<<<dim3((NB*DNUM+255)/256), blk, 0, stream>>>(x_num, XNh, XNl, (long long)NB*DNUM);
    split_k<<<dim3((NCAND*DNUM+255)/256), blk, 0, stream>>>(cand_x, CXh, CXl, (long long)NCAND*DNUM);

    /* ---- query encode ---- */
    gemm256<<<dim3(NB/64), blk, 0, stream>>>(XNh, XNl, WinTh, WinTl,
        ZF, HQ1h, HQ1l, ZU, b_in, ZCU, ZCU, 0, ZCF, ZCF, ZU, ZU, ZF,
        ZCU, ZCU, ZCU, ZCU, ZI, ZF, ZCF, NB, DNUM);
    gemm512<<<dim3(NB/64), blk, 0, stream>>>(HQ1h, HQ1l, We1Th, We1Tl,
        ZF, TQh, TQl, ZU, be1, ZCU, ZCU, 1, ZCF, ZCF, ZU, ZU, ZF,
        ZCU, ZCU, ZCU, ZCU, ZI, ZF, ZCF, NB, DM);
    gemm256<<<dim3(NB/64), blk, 0, stream>>>(TQh, TQl, We2Th, We2Tl,
        ZF, HQ2h, HQ2l, ZU, be2, HQ1h, HQ1l, 0, g_m, b_m, LNQh, LNQl, ZF,
        ZCU, ZCU, ZCU, ZCU, ZI, ZF, ZCF, NB, DH);
    gemm256<<<dim3(NB/64), blk, 0, stream>>>(LNQh, LNQl, WsTh, WsTl,
        ZF, KQh, KQl, ZU, bs, ZCU, ZCU, 0, ZCF, ZCF, ZU, ZU, ZF,
        ZCU, ZCU, ZCU, ZCU, ZI, ZF, ZCF, NB, DM);

    /* ---- candidate encode (chunks; fused LN; fused ||k||^2) ---- */
    for (int c0 = 0; c0 < NCAND; c0 += EC) {
        int gy = (EC + 63) / 64;
        gemm256<<<dim3(gy), blk, 0, stream>>>(CXh + (long long)c0*DNUM, CXl + (long long)c0*DNUM,
            WinTh, WinTl, ZF, Hch, Hcl, ZU, b_in, ZCU, ZCU, 0, ZCF, ZCF, ZU, ZU, ZF,
            ZCU, ZCU, ZCU, ZCU, ZI, ZF, ZCF, EC, DNUM);
        gemm512<<<dim3(gy), blk, 0, stream>>>(Hch, Hcl, We1Th, We1Tl,
            ZF, Tch, Tcl, ZU, be1, ZCU, ZCU, 1, ZCF, ZCF, ZU, ZU, ZF,
            ZCU, ZCU, ZCU, ZCU, ZI, ZF, ZCF, EC, DM);
        gemm256<<<dim3(gy), blk, 0, stream>>>(Tch, Tcl, We2Th, We2Tl,
            ZF, ZU, ZU, ZU, be2, Hch, Hcl, 0, g_m, b_m, LNch, LNcl, ZF,
            ZCU, ZCU, ZCU, ZCU, ZI, ZF, ZCF, EC, DH);
        gemm256<<<dim3(gy), blk, 0, stream>>>(LNch, LNcl, WsTh, WsTl,
            ZF, KCh + (long long)c0*DM, KCl + (long long)c0*DM, ZU, bs, ZCU, ZCU, 0,
            ZCF, ZCF, ZU, ZU, SC + c0,
            ZCU, ZCU, ZCU, ZCU, ZI, ZF, ZCF, EC, DM);
    }

    /* ---- sim (KC as A, queries as B; transposed write; 2*k.ck - ||ck||^2) + top-96 ---- */
    for (int q0 = 0; q0 < NB; q0 += QS) {
        if (QS == 512)
            gemm512<<<dim3((NCAND + 63) / 64), blk, 0, stream>>>(KCh, KCl,
                KQh + (long long)q0*DM, KQl + (long long)q0*DM,
                ZF, ZU, ZU, ZU, ZCF, ZCU, ZCU, 0, ZCF, ZCF, ZU, ZU, ZF,
                ZCU, ZCU, ZCU, ZCU, ZI, Sb, SC, NCAND, DM);
        else
            gemm256<<<dim3((NCAND + 63) / 64), blk, 0, stream>>>(KCh, KCl,
                KQh + (long long)q0*DM, KQl + (long long)q0*DM,
                ZF, ZU, ZU, ZU, ZCF, ZCU, ZCU, 0, ZCF, ZCF, ZU, ZU, ZF,
                ZCU, ZCU, ZCU, ZCU, ZI, Sb, SC, NCAND, DM);
        topk_k<<<dim3(QS), dim3(1024), 0, stream>>>(Sb, q0, IDX, PRB);
    }

    /* ---- value aggregation (gather fused into Wt1 GEMM A-staging) ---- */
    ybar_k<<<dim3(NB), blk, 0, stream>>>(PRB, IDX, cand_y, YB);
    for (int v0 = 0; v0 < NB; v0 += VC) {
        gemm512<<<dim3((VC * MCTX) / 64), blk, 0, stream>>>(ZCU, ZCU, Wt1Th, Wt1Tl,
            ZF, ZU, ZU, Ub, ZCF, ZCU, ZCU, 1, ZCF, ZCF, ZU, ZU, ZF,
            KQh + (long long)v0*DM, KQl + (long long)v0*DM, KCh, KCl, IDX + (long long)v0*MCTX,
            ZF, ZCF, VC * MCTX, DM);
        wsum_k<<<dim3(VC), dim3(512), 0, stream>>>(Ub, PRB + (long long)v0*MCTX, UQv + (long long)v0*DH);
    }
    split_k<<<dim3((NB*DH+255)/256), blk, 0, stream>>>(UQv, UQvh, UQvl, (long long)NB*DH);
    mixprep_sp<<<dim3(NB), blk, 0, stream>>>(HQ2h, HQ2l, YB, Wy, by, bt2);
    gemm256<<<dim3(NB/64), blk, 0, stream>>>(UQvh, UQvl, Wt2Th, Wt2Tl,
        ZF, XQh, XQl, ZU, ZCF, HQ2h, HQ2l, 0, ZCF, ZCF, ZU, ZU, ZF,
        ZCU, ZCU, ZCU, ZCU, ZI, ZF, ZCF, NB, DH);

    /* ---- predictor block + head ---- */
    gemm512<<<dim3(NB/64), blk, 0, stream>>>(XQh, XQl, Wp1Th, Wp1Tl,
        ZF, TQh, TQl, ZU, bp1, ZCU, ZCU, 1, ZCF, ZCF, ZU, ZU, ZF,
        ZCU, ZCU, ZCU, ZCU, ZI, ZF, ZCF, NB, DM);
    gemm256<<<dim3(NB/64), blk, 0, stream>>>(TQh, TQl, Wp2Th, Wp2Tl,
        XQ2f, ZU, ZU, ZU, bp2, XQh, XQl, 0, ZCF, ZCF, ZU, ZU, ZF,
        ZCU, ZCU, ZCU, ZCU, ZI, ZF, ZCF, NB, DH);
    head_k<<<dim3(NB), blk, 0, stream>>>(XQ2f, g_h, b_h, Wh, bh, out);
}

// Round 8
// 4292.709 us; speedup vs baseline: 3.3182x; 1.0178x over previous
//
#include <hip/hip_runtime.h>
#include <stdint.h>

#define NCAND 100000
#define NB    1024
#define DNUM  96
#define DM    256
#define DH    512
#define MCTX  96
#define LNEPS 1e-5f

typedef __bf16 bf16x8 __attribute__((ext_vector_type(8)));
typedef float  f32x4  __attribute__((ext_vector_type(4)));
typedef unsigned short u16x8 __attribute__((ext_vector_type(8)));
typedef unsigned short us;

__device__ __forceinline__ us f2bf(float x)
{
    unsigned u = __float_as_uint(x);
    unsigned r = u + 0x7FFFu + ((u >> 16) & 1u);   /* RNE */
    return (us)(r >> 16);
}
__device__ __forceinline__ float bfbits(us h)
{
    return __uint_as_float(((unsigned)h) << 16);
}

extern "C" __global__ __launch_bounds__(256)
void split_k(const float* X, us* Xh, us* Xl, long long n)
{
    long long i = (long long)blockIdx.x * 256 + threadIdx.x;
    if (i < n) {
        float x = X[i];
        us h = f2bf(x);
        Xh[i] = h;
        Xl[i] = f2bf(x - bfbits(h));
    }
}

extern "C" __global__ __launch_bounds__(256)
void splitT_k(const float* W, us* Th, us* Tl, int Kd, int Nd)
{
    int i = blockIdx.x * 256 + threadIdx.x;
    if (i < Kd * Nd) {
        int k = i / Nd, n2 = i - k * Nd;
        float x = W[i];
        us h = f2bf(x);
        Th[(long long)n2 * Kd + k] = h;
        Tl[(long long)n2 * Kd + k] = f2bf(x - bfbits(h));
    }
}

/* =====================================================================
   Direct-fragment split-bf16 MFMA GEMM (no LDS in the K-loop, no barriers).
   Block = 4 waves; wave w owns rows m0=blockIdx.x*64+w*16 (16 rows), cols
   n0=blockIdx.y*256 .. +256 (16 j-tiles). A[M,K], B[N,K] pre-split hi/lo
   bf16. acc = Ah*Bh + Ah*Bl + Al*Bh (f32, rel err ~1e-4).
   Fragment loads are 16 B/lane straight from global (L1/L2-served):
     A[m=lane&15][k=(lane>>4)*8+..], B[n=lane&15][k=..] per tile.
   Modes: bias / split-resid / relu; outputs f32 | split | bf16;
   fused LayerNorm (wave-local shfl stats; requires grid.y==1, N==256);
   fused row-sumsq (snOut); gather-A (row = kq[row/96]-kc[gidx[row]],
   plain-bf16 D, 2-pass); sim (write 2*acc-colb[cand] transposed into
   simT[q][cand], 16 B/lane; requires M%16==0). K%32==0.
   ===================================================================== */
extern "C" __global__ __launch_bounds__(256)
void gemm_d(const us* Ah, const us* Al, const us* BTh, const us* BTl,
            float* outF, us* outH, us* outL, us* outB16,
            const float* bias, const us* Rh, const us* Rl, int dorelu,
            const float* lng, const float* lnb, us* lnH, us* lnL,
            float* snOut,
            const us* Gqh, const us* Gql, const us* Gch, const us* Gcl,
            const int* gidx,
            float* simT, const float* colb,
            int M, int N, int K)
{
    int t = threadIdx.x, wave = t >> 6, lane = t & 63;
    int lm = lane & 15, lk = (lane >> 4) * 8, rb = (lane >> 4) * 4;
    int m0 = blockIdx.x * 64 + wave * 16;
    int n0 = blockIdx.y * 256;
    int arow = m0 + lm;

    f32x4 acc[16];
#pragma unroll
    for (int j = 0; j < 16; j++)
        for (int e = 0; e < 4; e++) acc[j][e] = 0.0f;

    int gb = 0, gc = 0;
    if (gidx && arow < M) { gb = arow / MCTX; gc = gidx[arow]; }

    for (int k0 = 0; k0 < K; k0 += 32) {
        u16x8 au = {0,0,0,0,0,0,0,0}, alu = au;
        if (arow < M) {
            if (!gidx) {
                au  = *(const u16x8*)(Ah + (long long)arow * K + k0 + lk);
                alu = *(const u16x8*)(Al + (long long)arow * K + k0 + lk);
            } else {
                u16x8 qh = *(const u16x8*)(Gqh + (long long)gb * DM + k0 + lk);
                u16x8 ql = *(const u16x8*)(Gql + (long long)gb * DM + k0 + lk);
                u16x8 ch = *(const u16x8*)(Gch + (long long)gc * DM + k0 + lk);
                u16x8 cl = *(const u16x8*)(Gcl + (long long)gc * DM + k0 + lk);
#pragma unroll
                for (int e = 0; e < 8; e++) {
                    float v = (bfbits(qh[e]) + bfbits(ql[e]))
                            - (bfbits(ch[e]) + bfbits(cl[e]));
                    au[e] = f2bf(v);
                }
            }
        }
        bf16x8 fah = *(bf16x8*)&au;
        bf16x8 fal = *(bf16x8*)&alu;
#pragma unroll
        for (int j = 0; j < 16; j++) {
            long long bro = (long long)(n0 + j * 16 + lm) * K + k0 + lk;
            u16x8 bu  = *(const u16x8*)(BTh + bro);
            u16x8 blu = *(const u16x8*)(BTl + bro);
            bf16x8 fbh = *(bf16x8*)&bu;
            bf16x8 fbl = *(bf16x8*)&blu;
            acc[j] = __builtin_amdgcn_mfma_f32_16x16x32_bf16(fah, fbh, acc[j], 0, 0, 0);
            acc[j] = __builtin_amdgcn_mfma_f32_16x16x32_bf16(fah, fbl, acc[j], 0, 0, 0);
            if (!gidx)
                acc[j] = __builtin_amdgcn_mfma_f32_16x16x32_bf16(fal, fbh, acc[j], 0, 0, 0);
        }
    }

    /* C/D layout: col = lane&15 (within j-tile), row = (lane>>4)*4 + e */
    if (simT) {
        if (m0 < M) {                 /* M % 16 == 0 in sim mode */
#pragma unroll
            for (int j = 0; j < 16; j++) {
                int q = n0 + j * 16 + lm;
                f32x4 v;
                for (int e = 0; e < 4; e++)
                    v[e] = 2.0f * acc[j][e] - colb[m0 + rb + e];
                *(f32x4*)(simT + (long long)q * NCAND + m0 + rb) = v;
            }
        }
        return;
    }

    /* pass 1: bias/resid/relu into acc + primary outputs */
#pragma unroll
    for (int j = 0; j < 16; j++) {
        int col = n0 + j * 16 + lm;
        float bc = bias ? bias[col] : 0.0f;
        for (int e = 0; e < 4; e++) {
            int row = m0 + rb + e;
            float v = acc[j][e] + bc;
            if (row < M) {
                long long oix = (long long)row * N + col;
                if (Rh) v += bfbits(Rh[oix]) + bfbits(Rl[oix]);
                if (dorelu && v < 0.0f) v = 0.0f;
                if (outF)   outF[oix] = v;
                if (outB16) outB16[oix] = f2bf(v);
                if (outH) { us h = f2bf(v); outH[oix] = h; outL[oix] = f2bf(v - bfbits(h)); }
            } else {
                if (dorelu && v < 0.0f) v = 0.0f;
            }
            acc[j][e] = v;
        }
    }

    if (lng || snOut) {
        float mu4[4], rs4[4];
        for (int e = 0; e < 4; e++) {
            float s1 = 0.0f, s2 = 0.0f;
#pragma unroll
            for (int j = 0; j < 16; j++) { float v = acc[j][e]; s1 += v; s2 += v * v; }
            for (int o = 1; o < 16; o <<= 1) {
                s1 += __shfl_xor(s1, o, 64);
                s2 += __shfl_xor(s2, o, 64);
            }
            int row = m0 + rb + e;
            if (snOut && lm == 0 && row < M) snOut[row] = s2;
            float mu = s1 * (1.0f / 256.0f);
            float var = s2 * (1.0f / 256.0f) - mu * mu;
            mu4[e] = mu;
            rs4[e] = rsqrtf(var + LNEPS);
        }
        if (lng) {
#pragma unroll
            for (int j = 0; j < 16; j++) {
                int col = n0 + j * 16 + lm;
                float g = lng[col], bb = lnb[col];
                for (int e = 0; e < 4; e++) {
                    int row = m0 + rb + e;
                    if (row >= M) continue;
                    float y = (acc[j][e] - mu4[e]) * rs4[e] * g + bb;
                    long long oix = (long long)row * N + col;
                    us h = f2bf(y);
                    lnH[oix] = h;
                    lnL[oix] = f2bf(y - bfbits(h));
                }
            }
        }
    }
}

__device__ unsigned fmapf(float f)
{
    unsigned u = __float_as_uint(f);
    return u ^ (unsigned)(((int)u >> 31) | (int)0x80000000);
}

/* exact top-96 (radix select 4x8-bit, ties -> smallest index) + softmax */
extern "C" __global__ __launch_bounds__(1024)
void topk_k(const float* S, int q0, int* out_idx, float* out_p)
{
    int t = threadIdx.x;
    const float* row = S + (long long)blockIdx.x * NCAND;
    const float4* row4 = (const float4*)row;
    __shared__ int hist8[8][256];
    __shared__ unsigned sh_prefix;
    __shared__ int sh_want, cntG, cntE;
    __shared__ int   gidx[128];
    __shared__ float gval[128];
    __shared__ int   eqi[2048];
    __shared__ float vals[MCTX];
    __shared__ int   inds[MCTX];
    __shared__ float pr[MCTX];

    if (t == 0) { sh_prefix = 0u; sh_want = MCTX; cntG = 0; cntE = 0; }

    for (int lvl = 0; lvl < 4; lvl++) {
        int shift = 24 - 8 * lvl;
        for (int i = t; i < 2048; i += 1024) ((int*)hist8)[i] = 0;
        __syncthreads();
        unsigned prefix = sh_prefix;
        unsigned mask = (lvl == 0) ? 0u : (0xFFFFFFFFu << (shift + 8));
        int* hrow = hist8[t & 7];
        for (int c = t; c < NCAND / 4; c += 1024) {
            float4 v = row4[c];
            unsigned k0 = fmapf(v.x), k1 = fmapf(v.y), k2 = fmapf(v.z), k3 = fmapf(v.w);
            if ((k0 & mask) == prefix) atomicAdd(&hrow[(k0 >> shift) & 255], 1);
            if ((k1 & mask) == prefix) atomicAdd(&hrow[(k1 >> shift) & 255], 1);
            if ((k2 & mask) == prefix) atomicAdd(&hrow[(k2 >> shift) & 255], 1);
            if ((k3 & mask) == prefix) atomicAdd(&hrow[(k3 >> shift) & 255], 1);
        }
        __syncthreads();
        if (t < 256) {
            int s = 0;
            for (int g2 = 1; g2 < 8; g2++) s += hist8[g2][t];
            hist8[0][t] += s;
        }
        __syncthreads();
        if (t == 0) {
            int want = sh_want, cum = 0;
            for (int b2 = 255; b2 >= 0; b2--) {
                cum += hist8[0][b2];
                if (cum >= want) {
                    sh_want = want - (cum - hist8[0][b2]);
                    sh_prefix = prefix | ((unsigned)b2 << shift);
                    break;
                }
            }
        }
        __syncthreads();
    }
    unsigned T = sh_prefix;
    for (int c = t; c < NCAND / 4; c += 1024) {
        float4 v = row4[c];
        float vv[4]; vv[0] = v.x; vv[1] = v.y; vv[2] = v.z; vv[3] = v.w;
        for (int e = 0; e < 4; e++) {
            unsigned key = fmapf(vv[e]);
            if (key > T) {
                int p = atomicAdd(&cntG, 1);
                if (p < 128) { gidx[p] = c * 4 + e; gval[p] = vv[e]; }
            } else if (key == T) {
                int p = atomicAdd(&cntE, 1);
                if (p < 2048) eqi[p] = c * 4 + e;
            }
        }
    }
    __syncthreads();
    if (t == 0) {
        int nG = cntG; if (nG > MCTX) nG = MCTX;
        int nE = cntE; if (nE > 2048) nE = 2048;
        int need = MCTX - nG;
        for (int i = 0; i < nG; i++) { inds[i] = gidx[i]; vals[i] = gval[i]; }
        for (int s = 0; s < need; s++) {
            int best = 0x7FFFFFFF, bp = -1;
            for (int e = 0; e < nE; e++) if (eqi[e] < best) { best = eqi[e]; bp = e; }
            if (bp >= 0) { eqi[bp] = 0x7FFFFFFF; inds[nG + s] = best; vals[nG + s] = row[best]; }
            else         { inds[nG + s] = 0;     vals[nG + s] = -3.0e38f; }
        }
        float mx = -3.4e38f;
        for (int i = 0; i < MCTX; i++) if (vals[i] > mx) mx = vals[i];
        float sum = 0.0f;
        for (int i = 0; i < MCTX; i++) { float e = expf(vals[i] - mx); pr[i] = e; sum += e; }
        float inv = 1.0f / sum;
        for (int i = 0; i < MCTX; i++) pr[i] *= inv;
    }
    __syncthreads();
    if (t < MCTX) {
        long long o = (long long)(q0 + blockIdx.x) * MCTX + t;
        out_idx[o] = inds[t];
        out_p[o]   = pr[t];
    }
}

extern "C" __global__ __launch_bounds__(256)
void ybar_k(const float* P, const int* idx, const float* y, float* ybar)
{
    __shared__ float sred[256];
    int b = blockIdx.x, t = threadIdx.x;
    float v = 0.0f;
    if (t < MCTX) v = P[(long long)b * MCTX + t] * y[idx[(long long)b * MCTX + t]];
    sred[t] = v; __syncthreads();
    for (int s = 128; s > 0; s >>= 1) { if (t < s) sred[t] += sred[t + s]; __syncthreads(); }
    if (t == 0) ybar[b] = sred[0];
}

/* tier A: u[b,j] = sum_m p_m * relu(Pq[b,j] - R[idx_m, j]) */
extern "C" __global__ __launch_bounds__(512)
void wsum2_k(const float* Pq, const float* R, const float* P, const int* idx, float* u)
{
    __shared__ float pl[MCTX];
    __shared__ int ix[MCTX];
    int b = blockIdx.x, j = threadIdx.x;
    if (j < MCTX) {
        pl[j] = P[(long long)b * MCTX + j];
        ix[j] = idx[(long long)b * MCTX + j];
    }
    __syncthreads();
    float pb = Pq[(long long)b * DH + j];
    float a = 0.0f;
    for (int m = 0; m < MCTX; m++) {
        float d = pb - R[(long long)ix[m] * DH + j];
        a += pl[m] * (d > 0.0f ? d : 0.0f);
    }
    u[(long long)b * DH + j] = a;
}

/* tier B fallback: u[b,j] = sum_m p_m * U[(b,m),j], U plain bf16 */
extern "C" __global__ __launch_bounds__(512)
void wsum_k(const us* U, const float* P, float* u)
{
    __shared__ float pl[MCTX];
    int b = blockIdx.x, j = threadIdx.x;
    if (j < MCTX) pl[j] = P[(long long)b * MCTX + j];
    __syncthreads();
    const us* Ub = U + (long long)b * MCTX * DH;
    float acc = 0.0f;
    for (int m = 0; m < MCTX; m++) acc += pl[m] * bfbits(Ub[(long long)m * DH + j]);
    u[(long long)b * DH + j] = acc;
}

extern "C" __global__ __launch_bounds__(256)
void mixprep_sp(us* h2h, us* h2l, const float* ybar,
                const float* Wy, const float* by, const float* bt2)
{
    int b = blockIdx.x, d = threadIdx.x;
    long long i = (long long)b * DM + d;
    float v = bfbits(h2h[i]) + bfbits(h2l[i]) + ybar[b] * Wy[d] + by[d] + bt2[d];
    us h = f2bf(v);
    h2h[i] = h;
    h2l[i] = f2bf(v - bfbits(h));
}

extern "C" __global__ __launch_bounds__(256)
void head_k(const float* X, const float* g, const float* bln, const float* Wh,
            const float* bh, float* out)
{
    __shared__ float sred[256];
    int r = blockIdx.x, t = threadIdx.x;
    float x = X[(long long)r * DM + t];
    sred[t] = x; __syncthreads();
    for (int s = 128; s > 0; s >>= 1) { if (t < s) sred[t] += sred[t + s]; __syncthreads(); }
    float mu = sred[0] * (1.0f / DM); __syncthreads();
    float d = x - mu;
    sred[t] = d * d; __syncthreads();
    for (int s = 128; s > 0; s >>= 1) { if (t < s) sred[t] += sred[t + s]; __syncthreads(); }
    float var = sred[0] * (1.0f / DM); __syncthreads();
    float ln = d * rsqrtf(var + LNEPS) * g[t] + bln[t];
    float rl = (ln > 0.0f) ? ln : 0.0f;
    sred[t] = rl * Wh[t]; __syncthreads();
    for (int s = 128; s > 0; s >>= 1) { if (t < s) sred[t] += sred[t + s]; __syncthreads(); }
    if (t == 0) out[r] = sred[0] + bh[0];
}

#define ZU (us*)0
#define ZCU (const us*)0
#define ZF (float*)0
#define ZCF (const float*)0
#define ZI (const int*)0

extern "C" void kernel_launch(void* const* d_in, const int* in_sizes, int n_in,
                              void* d_out, int out_size, void* d_ws, size_t ws_size,
                              hipStream_t stream)
{
    const float* x_num  = (const float*)d_in[0];
    const float* cand_x = (const float*)d_in[1];
    const float* cand_y = (const float*)d_in[2];
    const float* W_in = (const float*)d_in[4];
    const float* b_in = (const float*)d_in[5];
    const float* We1  = (const float*)d_in[6];
    const float* be1  = (const float*)d_in[7];
    const float* We2  = (const float*)d_in[8];
    const float* be2  = (const float*)d_in[9];
    const float* g_m  = (const float*)d_in[10];
    const float* b_m  = (const float*)d_in[11];
    const float* Ws   = (const float*)d_in[12];
    const float* bs   = (const float*)d_in[13];
    const float* Wy   = (const float*)d_in[14];
    const float* by   = (const float*)d_in[15];
    const float* Wt1  = (const float*)d_in[16];
    const float* Wt2  = (const float*)d_in[17];
    const float* bt2  = (const float*)d_in[18];
    const float* Wp1  = (const float*)d_in[19];
    const float* bp1  = (const float*)d_in[20];
    const float* Wp2  = (const float*)d_in[21];
    const float* bp2  = (const float*)d_in[22];
    const float* g_h  = (const float*)d_in[23];
    const float* b_h  = (const float*)d_in[24];
    const float* Wh   = (const float*)d_in[25];
    const float* bh   = (const float*)d_in[26];
    float* out = (float*)d_out;

    char* p = (char*)d_ws;
    us* WinTh = (us*)p; p += 256*96*2;   us* WinTl = (us*)p; p += 256*96*2;
    us* We1Th = (us*)p; p += 512*256*2;  us* We1Tl = (us*)p; p += 512*256*2;
    us* We2Th = (us*)p; p += 256*512*2;  us* We2Tl = (us*)p; p += 256*512*2;
    us* WsTh  = (us*)p; p += 256*256*2;  us* WsTl  = (us*)p; p += 256*256*2;
    us* Wt1Th = (us*)p; p += 512*256*2;  us* Wt1Tl = (us*)p; p += 512*256*2;
    us* Wt2Th = (us*)p; p += 256*512*2;  us* Wt2Tl = (us*)p; p += 256*512*2;
    us* Wp1Th = (us*)p; p += 512*256*2;  us* Wp1Tl = (us*)p; p += 512*256*2;
    us* Wp2Th = (us*)p; p += 256*512*2;  us* Wp2Tl = (us*)p; p += 256*512*2;
    us* XNh  = (us*)p; p += (long long)NB*DNUM*2;  us* XNl  = (us*)p; p += (long long)NB*DNUM*2;
    us* HQ1h = (us*)p; p += (long long)NB*DM*2;    us* HQ1l = (us*)p; p += (long long)NB*DM*2;
    us* TQh  = (us*)p; p += (long long)NB*DH*2;    us* TQl  = (us*)p; p += (long long)NB*DH*2;
    us* HQ2h = (us*)p; p += (long long)NB*DM*2;    us* HQ2l = (us*)p; p += (long long)NB*DM*2;
    us* LNQh = (us*)p; p += (long long)NB*DM*2;    us* LNQl = (us*)p; p += (long long)NB*DM*2;
    us* KQh  = (us*)p; p += (long long)NB*DM*2;    us* KQl  = (us*)p; p += (long long)NB*DM*2;
    us* XQh  = (us*)p; p += (long long)NB*DM*2;    us* XQl  = (us*)p; p += (long long)NB*DM*2;
    us* UQvh = (us*)p; p += (long long)NB*DH*2;    us* UQvl = (us*)p; p += (long long)NB*DH*2;
    float* UQv  = (float*)p; p += (long long)NB*DH*4;
    float* Pq   = (float*)p; p += (long long)NB*DH*4;
    float* XQ2f = (float*)p; p += (long long)NB*DM*4;
    float* YB   = (float*)p; p += (long long)NB*4;
    int*   IDX  = (int*)p;   p += (long long)NB*MCTX*4;
    float* PRB  = (float*)p; p += (long long)NB*MCTX*4;
    us* KCh = (us*)p; p += (long long)NCAND*DM*2;  us* KCl = (us*)p; p += (long long)NCAND*DM*2;
    float* SC = (float*)p; p += (long long)NCAND*4;

    size_t used = (size_t)(p - (char*)d_ws);
    long long avail = (ws_size > used + 4096) ? (long long)(ws_size - used - 4096) : 0;
    int EC = 6250;
    if      (avail >= 243300000LL) EC = 50000;
    else if (avail >= 141000000LL) EC = 25000;
    else if (avail >=  89700000LL) EC = 12500;
    int QS = (avail >= 204800000LL) ? 512 : 256;
    int tierA = (avail >= 204800000LL) ? 1 : 0;
    int VC = (avail >= 100700000LL) ? 1024 : 512;

    /* arena overlays (phases stream-sequential):
       phase1: CX split (38.4 MB) + Hc/Tc/LNc   phase2: Sb   phase3: R or Ub */
    char* AR = p;
    us* CXh = (us*)AR;
    us* CXl = CXh + (long long)NCAND*DNUM;
    char* EB = AR + (long long)NCAND*DNUM*4;
    us* Hch  = (us*)EB;                              us* Hcl  = Hch + (long long)EC*DM;
    us* Tch  = (us*)(EB + (long long)EC*DM*4);       us* Tcl  = Tch + (long long)EC*DH;
    us* LNch = (us*)(EB + (long long)EC*(DM+DH)*4);  us* LNcl = LNch + (long long)EC*DM;
    float* Sb = (float*)AR;
    float* R  = (float*)AR;
    us* Ub = (us*)AR;

    dim3 blk(256);

    /* ---- one-time splits ---- */
    splitT_k<<<dim3((DNUM*DM+255)/256), blk, 0, stream>>>(W_in, WinTh, WinTl, DNUM, DM);
    splitT_k<<<dim3((DM*DH+255)/256), blk, 0, stream>>>(We1, We1Th, We1Tl, DM, DH);
    splitT_k<<<dim3((DH*DM+255)/256), blk, 0, stream>>>(We2, We2Th, We2Tl, DH, DM);
    splitT_k<<<dim3((DM*DM+255)/256), blk, 0, stream>>>(Ws,  WsTh,  WsTl,  DM, DM);
    splitT_k<<<dim3((DM*DH+255)/256), blk, 0, stream>>>(Wt1, Wt1Th, Wt1Tl, DM, DH);
    splitT_k<<<dim3((DH*DM+255)/256), blk, 0, stream>>>(Wt2, Wt2Th, Wt2Tl, DH, DM);
    splitT_k<<<dim3((DM*DH+255)/256), blk, 0, stream>>>(Wp1, Wp1Th, Wp1Tl, DM, DH);
    splitT_k<<<dim3((DH*DM+255)/256), blk, 0, stream>>>(Wp2, Wp2Th, Wp2Tl, DH, DM);
    split_k<<<dim3((NB*DNUM+255)/256), blk, 0, stream>>>(x_num, XNh, XNl, (long long)NB*DNUM);
    split_k<<<dim3((NCAND*DNUM+255)/256), blk, 0, stream>>>(cand_x, CXh, CXl, (long long)NCAND*DNUM);

    /* ---- query encode ---- */
    gemm_d<<<dim3(NB/64, 1), blk, 0, stream>>>(XNh, XNl, WinTh, WinTl,
        ZF, HQ1h, HQ1l, ZU, b_in, ZCU, ZCU, 0, ZCF, ZCF, ZU, ZU, ZF,
        ZCU, ZCU, ZCU, ZCU, ZI, ZF, ZCF, NB, DM, DNUM);
    gemm_d<<<dim3(NB/64, 2), blk, 0, stream>>>(HQ1h, HQ1l, We1Th, We1Tl,
        ZF, TQh, TQl, ZU, be1, ZCU, ZCU, 1, ZCF, ZCF, ZU, ZU, ZF,
        ZCU, ZCU, ZCU, ZCU, ZI, ZF, ZCF, NB, DH, DM);
    gemm_d<<<dim3(NB/64, 1), blk, 0, stream>>>(TQh, TQl, We2Th, We2Tl,
        ZF, HQ2h, HQ2l, ZU, be2, HQ1h, HQ1l, 0, g_m, b_m, LNQh, LNQl, ZF,
        ZCU, ZCU, ZCU, ZCU, ZI, ZF, ZCF, NB, DM, DH);
    gemm_d<<<dim3(NB/64, 1), blk, 0, stream>>>(LNQh, LNQl, WsTh, WsTl,
        ZF, KQh, KQl, ZU, bs, ZCU, ZCU, 0, ZCF, ZCF, ZU, ZU, ZF,
        ZCU, ZCU, ZCU, ZCU, ZI, ZF, ZCF, NB, DM, DM);

    /* ---- candidate encode (fused LN, fused ||k||^2) ---- */
    for (int c0 = 0; c0 < NCAND; c0 += EC) {
        int gx = (EC + 63) / 64;
        gemm_d<<<dim3(gx, 1), blk, 0, stream>>>(CXh + (long long)c0*DNUM, CXl + (long long)c0*DNUM,
            WinTh, WinTl, ZF, Hch, Hcl, ZU, b_in, ZCU, ZCU, 0, ZCF, ZCF, ZU, ZU, ZF,
            ZCU, ZCU, ZCU, ZCU, ZI, ZF, ZCF, EC, DM, DNUM);
        gemm_d<<<dim3(gx, 2), blk, 0, stream>>>(Hch, Hcl, We1Th, We1Tl,
            ZF, Tch, Tcl, ZU, be1, ZCU, ZCU, 1, ZCF, ZCF, ZU, ZU, ZF,
            ZCU, ZCU, ZCU, ZCU, ZI, ZF, ZCF, EC, DH, DM);
        gemm_d<<<dim3(gx, 1), blk, 0, stream>>>(Tch, Tcl, We2Th, We2Tl,
            ZF, ZU, ZU, ZU, be2, Hch, Hcl, 0, g_m, b_m, LNch, LNcl, ZF,
            ZCU, ZCU, ZCU, ZCU, ZI, ZF, ZCF, EC, DM, DH);
        gemm_d<<<dim3(gx, 1), blk, 0, stream>>>(LNch, LNcl, WsTh, WsTl,
            ZF, KCh + (long long)c0*DM, KCl + (long long)c0*DM, ZU, bs, ZCU, ZCU, 0,
            ZCF, ZCF, ZU, ZU, SC + c0,
            ZCU, ZCU, ZCU, ZCU, ZI, ZF, ZCF, EC, DM, DM);
    }

    /* ---- sim (2*k.ck - ||ck||^2, transposed write) + exact top-96 ---- */
    for (int q0 = 0; q0 < NB; q0 += QS) {
        gemm_d<<<dim3((NCAND + 63) / 64, QS / 256), blk, 0, stream>>>(KCh, KCl,
            KQh + (long long)q0*DM, KQl + (long long)q0*DM,
            ZF, ZU, ZU, ZU, ZCF, ZCU, ZCU, 0, ZCF, ZCF, ZU, ZU, ZF,
            ZCU, ZCU, ZCU, ZCU, ZI, Sb, SC, NCAND, QS, DM);
        topk_k<<<dim3(QS), dim3(1024), 0, stream>>>(Sb, q0, IDX, PRB);
    }

    /* ---- value aggregation ---- */
    ybar_k<<<dim3(NB), blk, 0, stream>>>(PRB, IDX, cand_y, YB);
    gemm_d<<<dim3(NB/64, 2), blk, 0, stream>>>(KQh, KQl, Wt1Th, Wt1Tl,
        Pq, ZU, ZU, ZU, ZCF, ZCU, ZCU, 0, ZCF, ZCF, ZU, ZU, ZF,
        ZCU, ZCU, ZCU, ZCU, ZI, ZF, ZCF, NB, DH, DM);
    if (tierA) {
        /* R = KC @ Wt1 (f32), then u_b = sum_m p_m relu(Pq_b - R_cm) */
        gemm_d<<<dim3((NCAND + 63) / 64, 2), blk, 0, stream>>>(KCh, KCl, Wt1Th, Wt1Tl,
            R, ZU, ZU, ZU, ZCF, ZCU, ZCU, 0, ZCF, ZCF, ZU, ZU, ZF,
            ZCU, ZCU, ZCU, ZCU, ZI, ZF, ZCF, NCAND, DH, DM);
        wsum2_k<<<dim3(NB), dim3(512), 0, stream>>>(Pq, R, PRB, IDX, UQv);
    } else {
        for (int v0 = 0; v0 < NB; v0 += VC) {
            gemm_d<<<dim3((VC * MCTX) / 64, 2), blk, 0, stream>>>(ZCU, ZCU, Wt1Th, Wt1Tl,
                ZF, ZU, ZU, Ub, ZCF, ZCU, ZCU, 1, ZCF, ZCF, ZU, ZU, ZF,
                KQh + (long long)v0*DM, KQl + (long long)v0*DM, KCh, KCl,
                IDX + (long long)v0*MCTX, ZF, ZCF, VC * MCTX, DH, DM);
            wsum_k<<<dim3(VC), dim3(512), 0, stream>>>(Ub, PRB + (long long)v0*MCTX,
                                                       UQv + (long long)v0*DH);
        }
    }
    split_k<<<dim3((NB*DH+255)/256), blk, 0, stream>>>(UQv, UQvh, UQvl, (long long)NB*DH);
    mixprep_sp<<<dim3(NB), blk, 0, stream>>>(HQ2h, HQ2l, YB, Wy, by, bt2);
    gemm_d<<<dim3(NB/64, 1), blk, 0, stream>>>(UQvh, UQvl, Wt2Th, Wt2Tl,
        ZF, XQh, XQl, ZU, ZCF, HQ2h, HQ2l, 0, ZCF, ZCF, ZU, ZU, ZF,
        ZCU, ZCU, ZCU, ZCU, ZI, ZF, ZCF, NB, DM, DH);

    /* ---- predictor block + head ---- */
    gemm_d<<<dim3(NB/64, 2), blk, 0, stream>>>(XQh, XQl, Wp1Th, Wp1Tl,
        ZF, TQh, TQl, ZU, bp1, ZCU, ZCU, 1, ZCF, ZCF, ZU, ZU, ZF,
        ZCU, ZCU, ZCU, ZCU, ZI, ZF, ZCF, NB, DH, DM);
    gemm_d<<<dim3(NB/64, 1), blk, 0, stream>>>(TQh, TQl, Wp2Th, Wp2Tl,
        XQ2f, ZU, ZU, ZU, bp2, XQh, XQl, 0, ZCF, ZCF, ZU, ZU, ZF,
        ZCU, ZCU, ZCU, ZCU, ZI, ZF, ZCF, NB, DM, DH);
    head_k<<<dim3(NB), blk, 0, stream>>>(XQ2f, g_h, b_h, Wh, bh, out);
}

// Round 9
// 3561.133 us; speedup vs baseline: 3.9999x; 1.2054x over previous
//
#include <hip/hip_runtime.h>
#include <stdint.h>

#define NCAND 100000
#define NB    1024
#define DNUM  96
#define DM    256
#define DH    512
#define MCTX  96
#define LNEPS 1e-5f

typedef __bf16 bf16x8 __attribute__((ext_vector_type(8)));
typedef float  f32x4  __attribute__((ext_vector_type(4)));
typedef unsigned short u16x8 __attribute__((ext_vector_type(8)));
typedef unsigned short us;

__device__ __forceinline__ us f2bf(float x)
{
    unsigned u = __float_as_uint(x);
    unsigned r = u + 0x7FFFu + ((u >> 16) & 1u);   /* RNE */
    return (us)(r >> 16);
}
__device__ __forceinline__ float bfbits(us h)
{
    return __uint_as_float(((unsigned)h) << 16);
}

extern "C" __global__ __launch_bounds__(256)
void split_k(const float* X, us* Xh, us* Xl, long long n)
{
    long long i = (long long)blockIdx.x * 256 + threadIdx.x;
    if (i < n) {
        float x = X[i];
        us h = f2bf(x);
        Xh[i] = h;
        Xl[i] = f2bf(x - bfbits(h));
    }
}

/* ---- pack weight W[Kd,Nd] (f32) into split-bf16 MFMA B-fragment order:
   elem i = ((jt*(Kd/32)+kt)*64+lane)*8+e  <->  n=jt*16+(lane&15),
   k=kt*32+(lane>>4)*8+e.  A wave's B-tile load becomes 1 contiguous KB. ---- */
extern "C" __global__ __launch_bounds__(256)
void packW_k(const float* W, us* Ph, us* Pl, int Kd, int Nd)
{
    int i = blockIdx.x * 256 + threadIdx.x;
    if (i >= Kd * Nd) return;
    int e = i & 7, lane = (i >> 3) & 63, r = i >> 9;
    int KT = Kd >> 5;
    int kt = r % KT, jt = r / KT;
    int n = jt * 16 + (lane & 15);
    int k = kt * 32 + (lane >> 4) * 8 + e;
    float x = W[(long long)k * Nd + n];
    us h = f2bf(x);
    Ph[i] = h;
    Pl[i] = f2bf(x - bfbits(h));
}

/* ---- repack already-split rows R[N,Kd] into B-fragment order ---- */
extern "C" __global__ __launch_bounds__(256)
void packR_k(const us* Rh, const us* Rl, us* Ph, us* Pl, int Kd, int total)
{
    int i = blockIdx.x * 256 + threadIdx.x;
    if (i >= total) return;
    int e = i & 7, lane = (i >> 3) & 63, r = i >> 9;
    int KT = Kd >> 5;
    int kt = r % KT, jt = r / KT;
    int n = jt * 16 + (lane & 15);
    int k = kt * 32 + (lane >> 4) * 8 + e;
    Ph[i] = Rh[(long long)n * Kd + k];
    Pl[i] = Rl[(long long)n * Kd + k];
}

/* =====================================================================
   Direct-fragment split-bf16 MFMA GEMM; B pre-packed in fragment order
   (coalesced 1KB/wave tile loads). Block = 4 waves; wave w owns rows
   m0=blockIdx.x*64+w*16, cols n0=blockIdx.y*256..+256 (16 j-tiles).
   A[M,K] split rows; acc = Ah*Bh + Ah*Bl + Al*Bh (f32, rel err ~1e-4).
   Modes as before: bias/split-resid/relu; f32|split|bf16 out; fused LN
   (grid.y==1, N==256); fused row-sumsq; gather-A; sim transposed write.
   K%32==0.
   ===================================================================== */
extern "C" __global__ __launch_bounds__(256)
void gemm_d(const us* Ah, const us* Al, const us* BPh, const us* BPl,
            float* outF, us* outH, us* outL, us* outB16,
            const float* bias, const us* Rh, const us* Rl, int dorelu,
            const float* lng, const float* lnb, us* lnH, us* lnL,
            float* snOut,
            const us* Gqh, const us* Gql, const us* Gch, const us* Gcl,
            const int* gidx,
            float* simT, const float* colb,
            int M, int N, int K)
{
    int t = threadIdx.x, wave = t >> 6, lane = t & 63;
    int lm = lane & 15, lk = (lane >> 4) * 8, rb = (lane >> 4) * 4;
    int m0 = blockIdx.x * 64 + wave * 16;
    int n0 = blockIdx.y * 256;
    int arow = m0 + lm;
    int KT = K >> 5;

    f32x4 acc[16];
#pragma unroll
    for (int j = 0; j < 16; j++)
        for (int e = 0; e < 4; e++) acc[j][e] = 0.0f;

    int gb = 0, gc = 0;
    if (gidx && arow < M) { gb = arow / MCTX; gc = gidx[arow]; }

    for (int kt = 0; kt < KT; kt++) {
        int k0 = kt * 32;
        u16x8 au = {0,0,0,0,0,0,0,0}, alu = au;
        if (arow < M) {
            if (!gidx) {
                au  = *(const u16x8*)(Ah + (long long)arow * K + k0 + lk);
                alu = *(const u16x8*)(Al + (long long)arow * K + k0 + lk);
            } else {
                u16x8 qh = *(const u16x8*)(Gqh + (long long)gb * DM + k0 + lk);
                u16x8 ql = *(const u16x8*)(Gql + (long long)gb * DM + k0 + lk);
                u16x8 ch = *(const u16x8*)(Gch + (long long)gc * DM + k0 + lk);
                u16x8 cl = *(const u16x8*)(Gcl + (long long)gc * DM + k0 + lk);
#pragma unroll
                for (int e = 0; e < 8; e++) {
                    float v = (bfbits(qh[e]) + bfbits(ql[e]))
                            - (bfbits(ch[e]) + bfbits(cl[e]));
                    au[e] = f2bf(v);
                }
            }
        }
        bf16x8 fah = *(bf16x8*)&au;
        bf16x8 fal = *(bf16x8*)&alu;
#pragma unroll
        for (int j = 0; j < 16; j++) {
            long long bo = ((long long)((n0 >> 4) + j) * KT + kt) * 512 + lane * 8;
            u16x8 bu  = *(const u16x8*)(BPh + bo);
            u16x8 blu = *(const u16x8*)(BPl + bo);
            bf16x8 fbh = *(bf16x8*)&bu;
            bf16x8 fbl = *(bf16x8*)&blu;
            acc[j] = __builtin_amdgcn_mfma_f32_16x16x32_bf16(fah, fbh, acc[j], 0, 0, 0);
            acc[j] = __builtin_amdgcn_mfma_f32_16x16x32_bf16(fah, fbl, acc[j], 0, 0, 0);
            if (!gidx)
                acc[j] = __builtin_amdgcn_mfma_f32_16x16x32_bf16(fal, fbh, acc[j], 0, 0, 0);
        }
    }

    /* C/D layout: col = lane&15 (within j-tile), row = (lane>>4)*4 + e */
    if (simT) {
        if (m0 < M) {                 /* M % 16 == 0 in sim mode */
#pragma unroll
            for (int j = 0; j < 16; j++) {
                int q = n0 + j * 16 + lm;
                f32x4 v;
                for (int e = 0; e < 4; e++)
                    v[e] = 2.0f * acc[j][e] - colb[m0 + rb + e];
                *(f32x4*)(simT + (long long)q * NCAND + m0 + rb) = v;
            }
        }
        return;
    }

    /* pass 1: bias/resid/relu into acc + primary outputs */
#pragma unroll
    for (int j = 0; j < 16; j++) {
        int col = n0 + j * 16 + lm;
        float bc = bias ? bias[col] : 0.0f;
        for (int e = 0; e < 4; e++) {
            int row = m0 + rb + e;
            float v = acc[j][e] + bc;
            if (row < M) {
                long long oix = (long long)row * N + col;
                if (Rh) v += bfbits(Rh[oix]) + bfbits(Rl[oix]);
                if (dorelu && v < 0.0f) v = 0.0f;
                if (outF)   outF[oix] = v;
                if (outB16) outB16[oix] = f2bf(v);
                if (outH) { us h = f2bf(v); outH[oix] = h; outL[oix] = f2bf(v - bfbits(h)); }
            } else {
                if (dorelu && v < 0.0f) v = 0.0f;
            }
            acc[j][e] = v;
        }
    }

    if (lng || snOut) {
        float mu4[4], rs4[4];
        for (int e = 0; e < 4; e++) {
            float s1 = 0.0f, s2 = 0.0f;
#pragma unroll
            for (int j = 0; j < 16; j++) { float v = acc[j][e]; s1 += v; s2 += v * v; }
            for (int o = 1; o < 16; o <<= 1) {
                s1 += __shfl_xor(s1, o, 64);
                s2 += __shfl_xor(s2, o, 64);
            }
            int row = m0 + rb + e;
            if (snOut && lm == 0 && row < M) snOut[row] = s2;
            float mu = s1 * (1.0f / 256.0f);
            float var = s2 * (1.0f / 256.0f) - mu * mu;
            mu4[e] = mu;
            rs4[e] = rsqrtf(var + LNEPS);
        }
        if (lng) {
#pragma unroll
            for (int j = 0; j < 16; j++) {
                int col = n0 + j * 16 + lm;
                float g = lng[col], bb = lnb[col];
                for (int e = 0; e < 4; e++) {
                    int row = m0 + rb + e;
                    if (row >= M) continue;
                    float y = (acc[j][e] - mu4[e]) * rs4[e] * g + bb;
                    long long oix = (long long)row * N + col;
                    us h = f2bf(y);
                    lnH[oix] = h;
                    lnL[oix] = f2bf(y - bfbits(h));
                }
            }
        }
    }
}

__device__ unsigned fmapf(float f)
{
    unsigned u = __float_as_uint(f);
    return u ^ (unsigned)(((int)u >> 31) | (int)0x80000000);
}

/* exact top-96 (radix select 4x8-bit, ties -> smallest index) + softmax */
extern "C" __global__ __launch_bounds__(1024)
void topk_k(const float* S, int q0, int* out_idx, float* out_p)
{
    int t = threadIdx.x;
    const float* row = S + (long long)blockIdx.x * NCAND;
    const float4* row4 = (const float4*)row;
    __shared__ int hist8[8][256];
    __shared__ unsigned sh_prefix;
    __shared__ int sh_want, cntG, cntE;
    __shared__ int   gidx[128];
    __shared__ float gval[128];
    __shared__ int   eqi[2048];
    __shared__ float vals[MCTX];
    __shared__ int   inds[MCTX];
    __shared__ float pr[MCTX];

    if (t == 0) { sh_prefix = 0u; sh_want = MCTX; cntG = 0; cntE = 0; }

    for (int lvl = 0; lvl < 4; lvl++) {
        int shift = 24 - 8 * lvl;
        for (int i = t; i < 2048; i += 1024) ((int*)hist8)[i] = 0;
        __syncthreads();
        unsigned prefix = sh_prefix;
        unsigned mask = (lvl == 0) ? 0u : (0xFFFFFFFFu << (shift + 8));
        int* hrow = hist8[t & 7];
        for (int c = t; c < NCAND / 4; c += 1024) {
            float4 v = row4[c];
            unsigned k0 = fmapf(v.x), k1 = fmapf(v.y), k2 = fmapf(v.z), k3 = fmapf(v.w);
            if ((k0 & mask) == prefix) atomicAdd(&hrow[(k0 >> shift) & 255], 1);
            if ((k1 & mask) == prefix) atomicAdd(&hrow[(k1 >> shift) & 255], 1);
            if ((k2 & mask) == prefix) atomicAdd(&hrow[(k2 >> shift) & 255], 1);
            if ((k3 & mask) == prefix) atomicAdd(&hrow[(k3 >> shift) & 255], 1);
        }
        __syncthreads();
        if (t < 256) {
            int s = 0;
            for (int g2 = 1; g2 < 8; g2++) s += hist8[g2][t];
            hist8[0][t] += s;
        }
        __syncthreads();
        if (t == 0) {
            int want = sh_want, cum = 0;
            for (int b2 = 255; b2 >= 0; b2--) {
                cum += hist8[0][b2];
                if (cum >= want) {
                    sh_want = want - (cum - hist8[0][b2]);
                    sh_prefix = prefix | ((unsigned)b2 << shift);
                    break;
                }
            }
        }
        __syncthreads();
    }
    unsigned T = sh_prefix;
    for (int c = t; c < NCAND / 4; c += 1024) {
        float4 v = row4[c];
        float vv[4]; vv[0] = v.x; vv[1] = v.y; vv[2] = v.z; vv[3] = v.w;
        for (int e = 0; e < 4; e++) {
            unsigned key = fmapf(vv[e]);
            if (key > T) {
                int p = atomicAdd(&cntG, 1);
                if (p < 128) { gidx[p] = c * 4 + e; gval[p] = vv[e]; }
            } else if (key == T) {
                int p = atomicAdd(&cntE, 1);
                if (p < 2048) eqi[p] = c * 4 + e;
            }
        }
    }
    __syncthreads();
    if (t == 0) {
        int nG = cntG; if (nG > MCTX) nG = MCTX;
        int nE = cntE; if (nE > 2048) nE = 2048;
        int need = MCTX - nG;
        for (int i = 0; i < nG; i++) { inds[i] = gidx[i]; vals[i] = gval[i]; }
        for (int s = 0; s < need; s++) {
            int best = 0x7FFFFFFF, bp = -1;
            for (int e = 0; e < nE; e++) if (eqi[e] < best) { best = eqi[e]; bp = e; }
            if (bp >= 0) { eqi[bp] = 0x7FFFFFFF; inds[nG + s] = best; vals[nG + s] = row[best]; }
            else         { inds[nG + s] = 0;     vals[nG + s] = -3.0e38f; }
        }
        float mx = -3.4e38f;
        for (int i = 0; i < MCTX; i++) if (vals[i] > mx) mx = vals[i];
        float sum = 0.0f;
        for (int i = 0; i < MCTX; i++) { float e = expf(vals[i] - mx); pr[i] = e; sum += e; }
        float inv = 1.0f / sum;
        for (int i = 0; i < MCTX; i++) pr[i] *= inv;
    }
    __syncthreads();
    if (t < MCTX) {
        long long o = (long long)(q0 + blockIdx.x) * MCTX + t;
        out_idx[o] = inds[t];
        out_p[o]   = pr[t];
    }
}

extern "C" __global__ __launch_bounds__(256)
void ybar_k(const float* P, const int* idx, const float* y, float* ybar)
{
    __shared__ float sred[256];
    int b = blockIdx.x, t = threadIdx.x;
    float v = 0.0f;
    if (t < MCTX) v = P[(long long)b * MCTX + t] * y[idx[(long long)b * MCTX + t]];
    sred[t] = v; __syncthreads();
    for (int s = 128; s > 0; s >>= 1) { if (t < s) sred[t] += sred[t + s]; __syncthreads(); }
    if (t == 0) ybar[b] = sred[0];
}

/* tier A: u[b,j] = sum_m p_m * relu(Pq[b,j] - R[idx_m, j]) */
extern "C" __global__ __launch_bounds__(512)
void wsum2_k(const float* Pq, const float* R, const float* P, const int* idx, float* u)
{
    __shared__ float pl[MCTX];
    __shared__ int ix[MCTX];
    int b = blockIdx.x, j = threadIdx.x;
    if (j < MCTX) {
        pl[j] = P[(long long)b * MCTX + j];
        ix[j] = idx[(long long)b * MCTX + j];
    }
    __syncthreads();
    float pb = Pq[(long long)b * DH + j];
    float a = 0.0f;
    for (int m = 0; m < MCTX; m++) {
        float d = pb - R[(long long)ix[m] * DH + j];
        a += pl[m] * (d > 0.0f ? d : 0.0f);
    }
    u[(long long)b * DH + j] = a;
}

/* tier B fallback: u[b,j] = sum_m p_m * U[(b,m),j], U plain bf16 */
extern "C" __global__ __launch_bounds__(512)
void wsum_k(const us* U, const float* P, float* u)
{
    __shared__ float pl[MCTX];
    int b = blockIdx.x, j = threadIdx.x;
    if (j < MCTX) pl[j] = P[(long long)b * MCTX + j];
    __syncthreads();
    const us* Ub = U + (long long)b * MCTX * DH;
    float acc = 0.0f;
    for (int m = 0; m < MCTX; m++) acc += pl[m] * bfbits(Ub[(long long)m * DH + j]);
    u[(long long)b * DH + j] = acc;
}

extern "C" __global__ __launch_bounds__(256)
void mixprep_sp(us* h2h, us* h2l, const float* ybar,
                const float* Wy, const float* by, const float* bt2)
{
    int b = blockIdx.x, d = threadIdx.x;
    long long i = (long long)b * DM + d;
    float v = bfbits(h2h[i]) + bfbits(h2l[i]) + ybar[b] * Wy[d] + by[d] + bt2[d];
    us h = f2bf(v);
    h2h[i] = h;
    h2l[i] = f2bf(v - bfbits(h));
}

extern "C" __global__ __launch_bounds__(256)
void head_k(const float* X, const float* g, const float* bln, const float* Wh,
            const float* bh, float* out)
{
    __shared__ float sred[256];
    int r = blockIdx.x, t = threadIdx.x;
    float x = X[(long long)r * DM + t];
    sred[t] = x; __syncthreads();
    for (int s = 128; s > 0; s >>= 1) { if (t < s) sred[t] += sred[t + s]; __syncthreads(); }
    float mu = sred[0] * (1.0f / DM); __syncthreads();
    float d = x - mu;
    sred[t] = d * d; __syncthreads();
    for (int s = 128; s > 0; s >>= 1) { if (t < s) sred[t] += sred[t + s]; __syncthreads(); }
    float var = sred[0] * (1.0f / DM); __syncthreads();
    float ln = d * rsqrtf(var + LNEPS) * g[t] + bln[t];
    float rl = (ln > 0.0f) ? ln : 0.0f;
    sred[t] = rl * Wh[t]; __syncthreads();
    for (int s = 128; s > 0; s >>= 1) { if (t < s) sred[t] += sred[t + s]; __syncthreads(); }
    if (t == 0) out[r] = sred[0] + bh[0];
}

#define ZU (us*)0
#define ZCU (const us*)0
#define ZF (float*)0
#define ZCF (const float*)0
#define ZI (const int*)0

extern "C" void kernel_launch(void* const* d_in, const int* in_sizes, int n_in,
                              void* d_out, int out_size, void* d_ws, size_t ws_size,
                              hipStream_t stream)
{
    const float* x_num  = (const float*)d_in[0];
    const float* cand_x = (const float*)d_in[1];
    const float* cand_y = (const float*)d_in[2];
    const float* W_in = (const float*)d_in[4];
    const float* b_in = (const float*)d_in[5];
    const float* We1  = (const float*)d_in[6];
    const float* be1  = (const float*)d_in[7];
    const float* We2  = (const float*)d_in[8];
    const float* be2  = (const float*)d_in[9];
    const float* g_m  = (const float*)d_in[10];
    const float* b_m  = (const float*)d_in[11];
    const float* Ws   = (const float*)d_in[12];
    const float* bs   = (const float*)d_in[13];
    const float* Wy   = (const float*)d_in[14];
    const float* by   = (const float*)d_in[15];
    const float* Wt1  = (const float*)d_in[16];
    const float* Wt2  = (const float*)d_in[17];
    const float* bt2  = (const float*)d_in[18];
    const float* Wp1  = (const float*)d_in[19];
    const float* bp1  = (const float*)d_in[20];
    const float* Wp2  = (const float*)d_in[21];
    const float* bp2  = (const float*)d_in[22];
    const float* g_h  = (const float*)d_in[23];
    const float* b_h  = (const float*)d_in[24];
    const float* Wh   = (const float*)d_in[25];
    const float* bh   = (const float*)d_in[26];
    float* out = (float*)d_out;

    char* p = (char*)d_ws;
    /* weight packs (MFMA B-fragment order) */
    us* WinPh = (us*)p; p += 256*96*2;   us* WinPl = (us*)p; p += 256*96*2;
    us* We1Ph = (us*)p; p += 512*256*2;  us* We1Pl = (us*)p; p += 512*256*2;
    us* We2Ph = (us*)p; p += 256*512*2;  us* We2Pl = (us*)p; p += 256*512*2;
    us* WsPh  = (us*)p; p += 256*256*2;  us* WsPl  = (us*)p; p += 256*256*2;
    us* Wt1Ph = (us*)p; p += 512*256*2;  us* Wt1Pl = (us*)p; p += 512*256*2;
    us* Wt2Ph = (us*)p; p += 256*512*2;  us* Wt2Pl = (us*)p; p += 256*512*2;
    us* Wp1Ph = (us*)p; p += 512*256*2;  us* Wp1Pl = (us*)p; p += 512*256*2;
    us* Wp2Ph = (us*)p; p += 256*512*2;  us* Wp2Pl = (us*)p; p += 256*512*2;
    us* XNh  = (us*)p; p += (long long)NB*DNUM*2;  us* XNl  = (us*)p; p += (long long)NB*DNUM*2;
    us* HQ1h = (us*)p; p += (long long)NB*DM*2;    us* HQ1l = (us*)p; p += (long long)NB*DM*2;
    us* TQh  = (us*)p; p += (long long)NB*DH*2;    us* TQl  = (us*)p; p += (long long)NB*DH*2;
    us* HQ2h = (us*)p; p += (long long)NB*DM*2;    us* HQ2l = (us*)p; p += (long long)NB*DM*2;
    us* LNQh = (us*)p; p += (long long)NB*DM*2;    us* LNQl = (us*)p; p += (long long)NB*DM*2;
    us* KQh  = (us*)p; p += (long long)NB*DM*2;    us* KQl  = (us*)p; p += (long long)NB*DM*2;
    us* KQPh = (us*)p; p += (long long)NB*DM*2;    us* KQPl = (us*)p; p += (long long)NB*DM*2;
    us* XQh  = (us*)p; p += (long long)NB*DM*2;    us* XQl  = (us*)p; p += (long long)NB*DM*2;
    us* UQvh = (us*)p; p += (long long)NB*DH*2;    us* UQvl = (us*)p; p += (long long)NB*DH*2;
    float* UQv  = (float*)p; p += (long long)NB*DH*4;
    float* Pq   = (float*)p; p += (long long)NB*DH*4;
    float* XQ2f = (float*)p; p += (long long)NB*DM*4;
    float* YB   = (float*)p; p += (long long)NB*4;
    int*   IDX  = (int*)p;   p += (long long)NB*MCTX*4;
    float* PRB  = (float*)p; p += (long long)NB*MCTX*4;
    us* KCh = (us*)p; p += (long long)NCAND*DM*2;  us* KCl = (us*)p; p += (long long)NCAND*DM*2;
    float* SC = (float*)p; p += (long long)NCAND*4;

    size_t used = (size_t)(p - (char*)d_ws);
    long long avail = (ws_size > used + 4096) ? (long long)(ws_size - used - 4096) : 0;
    int EC = 6250;
    if      (avail >= 243300000LL) EC = 50000;
    else if (avail >= 141000000LL) EC = 25000;
    else if (avail >=  89700000LL) EC = 12500;
    int QS = (avail >= 204800000LL) ? 512 : 256;
    int tierA = (avail >= 204800000LL) ? 1 : 0;
    int VC = (avail >= 100700000LL) ? 1024 : 512;

    /* arena overlays (phases stream-sequential):
       phase1: CX split + Hc/Tc/LNc   phase2: Sb   phase3: R or Ub */
    char* AR = p;
    us* CXh = (us*)AR;
    us* CXl = CXh + (long long)NCAND*DNUM;
    char* EB = AR + (long long)NCAND*DNUM*4;
    us* Hch  = (us*)EB;                              us* Hcl  = Hch + (long long)EC*DM;
    us* Tch  = (us*)(EB + (long long)EC*DM*4);       us* Tcl  = Tch + (long long)EC*DH;
    us* LNch = (us*)(EB + (long long)EC*(DM+DH)*4);  us* LNcl = LNch + (long long)EC*DM;
    float* Sb = (float*)AR;
    float* R  = (float*)AR;
    us* Ub = (us*)AR;

    dim3 blk(256);

    /* ---- one-time weight packs + activation splits ---- */
    packW_k<<<dim3((DNUM*DM+255)/256), blk, 0, stream>>>(W_in, WinPh, WinPl, DNUM, DM);
    packW_k<<<dim3((DM*DH+255)/256), blk, 0, stream>>>(We1, We1Ph, We1Pl, DM, DH);
    packW_k<<<dim3((DH*DM+255)/256), blk, 0, stream>>>(We2, We2Ph, We2Pl, DH, DM);
    packW_k<<<dim3((DM*DM+255)/256), blk, 0, stream>>>(Ws,  WsPh,  WsPl,  DM, DM);
    packW_k<<<dim3((DM*DH+255)/256), blk, 0, stream>>>(Wt1, Wt1Ph, Wt1Pl, DM, DH);
    packW_k<<<dim3((DH*DM+255)/256), blk, 0, stream>>>(Wt2, Wt2Ph, Wt2Pl, DH, DM);
    packW_k<<<dim3((DM*DH+255)/256), blk, 0, stream>>>(Wp1, Wp1Ph, Wp1Pl, DM, DH);
    packW_k<<<dim3((DH*DM+255)/256), blk, 0, stream>>>(Wp2, Wp2Ph, Wp2Pl, DH, DM);
    split_k<<<dim3((NB*DNUM+255)/256), blk, 0, stream>>>(x_num, XNh, XNl, (long long)NB*DNUM);
    split_k<<<dim3((NCAND*DNUM+255)/256), blk, 0, stream>>>(cand_x, CXh, CXl, (long long)NCAND*DNUM);

    /* ---- query encode ---- */
    gemm_d<<<dim3(NB/64, 1), blk, 0, stream>>>(XNh, XNl, WinPh, WinPl,
        ZF, HQ1h, HQ1l, ZU, b_in, ZCU, ZCU, 0, ZCF, ZCF, ZU, ZU, ZF,
        ZCU, ZCU, ZCU, ZCU, ZI, ZF, ZCF, NB, DM, DNUM);
    gemm_d<<<dim3(NB/64, 2), blk, 0, stream>>>(HQ1h, HQ1l, We1Ph, We1Pl,
        ZF, TQh, TQl, ZU, be1, ZCU, ZCU, 1, ZCF, ZCF, ZU, ZU, ZF,
        ZCU, ZCU, ZCU, ZCU, ZI, ZF, ZCF, NB, DH, DM);
    gemm_d<<<dim3(NB/64, 1), blk, 0, stream>>>(TQh, TQl, We2Ph, We2Pl,
        ZF, HQ2h, HQ2l, ZU, be2, HQ1h, HQ1l, 0, g_m, b_m, LNQh, LNQl, ZF,
        ZCU, ZCU, ZCU, ZCU, ZI, ZF, ZCF, NB, DM, DH);
    gemm_d<<<dim3(NB/64, 1), blk, 0, stream>>>(LNQh, LNQl, WsPh, WsPl,
        ZF, KQh, KQl, ZU, bs, ZCU, ZCU, 0, ZCF, ZCF, ZU, ZU, ZF,
        ZCU, ZCU, ZCU, ZCU, ZI, ZF, ZCF, NB, DM, DM);
    packR_k<<<dim3((NB*DM+255)/256), blk, 0, stream>>>(KQh, KQl, KQPh, KQPl, DM, NB*DM);

    /* ---- candidate encode (fused LN, fused ||k||^2) ---- */
    for (int c0 = 0; c0 < NCAND; c0 += EC) {
        int gx = (EC + 63) / 64;
        gemm_d<<<dim3(gx, 1), blk, 0, stream>>>(CXh + (long long)c0*DNUM, CXl + (long long)c0*DNUM,
            WinPh, WinPl, ZF, Hch, Hcl, ZU, b_in, ZCU, ZCU, 0, ZCF, ZCF, ZU, ZU, ZF,
            ZCU, ZCU, ZCU, ZCU, ZI, ZF, ZCF, EC, DM, DNUM);
        gemm_d<<<dim3(gx, 2), blk, 0, stream>>>(Hch, Hcl, We1Ph, We1Pl,
            ZF, Tch, Tcl, ZU, be1, ZCU, ZCU, 1, ZCF, ZCF, ZU, ZU, ZF,
            ZCU, ZCU, ZCU, ZCU, ZI, ZF, ZCF, EC, DH, DM);
        gemm_d<<<dim3(gx, 1), blk, 0, stream>>>(Tch, Tcl, We2Ph, We2Pl,
            ZF, ZU, ZU, ZU, be2, Hch, Hcl, 0, g_m, b_m, LNch, LNcl, ZF,
            ZCU, ZCU, ZCU, ZCU, ZI, ZF, ZCF, EC, DM, DH);
        gemm_d<<<dim3(gx, 1), blk, 0, stream>>>(LNch, LNcl, WsPh, WsPl,
            ZF, KCh + (long long)c0*DM, KCl + (long long)c0*DM, ZU, bs, ZCU, ZCU, 0,
            ZCF, ZCF, ZU, ZU, SC + c0,
            ZCU, ZCU, ZCU, ZCU, ZI, ZF, ZCF, EC, DM, DM);
    }

    /* ---- sim (2*k.ck - ||ck||^2, transposed write) + exact top-96 ---- */
    for (int q0 = 0; q0 < NB; q0 += QS) {
        gemm_d<<<dim3((NCAND + 63) / 64, QS / 256), blk, 0, stream>>>(KCh, KCl,
            KQPh + (long long)q0*DM, KQPl + (long long)q0*DM,
            ZF, ZU, ZU, ZU, ZCF, ZCU, ZCU, 0, ZCF, ZCF, ZU, ZU, ZF,
            ZCU, ZCU, ZCU, ZCU, ZI, Sb, SC, NCAND, QS, DM);
        topk_k<<<dim3(QS), dim3(1024), 0, stream>>>(Sb, q0, IDX, PRB);
    }

    /* ---- value aggregation ---- */
    ybar_k<<<dim3(NB), blk, 0, stream>>>(PRB, IDX, cand_y, YB);
    gemm_d<<<dim3(NB/64, 2), blk, 0, stream>>>(KQh, KQl, Wt1Ph, Wt1Pl,
        Pq, ZU, ZU, ZU, ZCF, ZCU, ZCU, 0, ZCF, ZCF, ZU, ZU, ZF,
        ZCU, ZCU, ZCU, ZCU, ZI, ZF, ZCF, NB, DH, DM);
    if (tierA) {
        gemm_d<<<dim3((NCAND + 63) / 64, 2), blk, 0, stream>>>(KCh, KCl, Wt1Ph, Wt1Pl,
            R, ZU, ZU, ZU, ZCF, ZCU, ZCU, 0, ZCF, ZCF, ZU, ZU, ZF,
            ZCU, ZCU, ZCU, ZCU, ZI, ZF, ZCF, NCAND, DH, DM);
        wsum2_k<<<dim3(NB), dim3(512), 0, stream>>>(Pq, R, PRB, IDX, UQv);
    } else {
        for (int v0 = 0; v0 < NB; v0 += VC) {
            gemm_d<<<dim3((VC * MCTX) / 64, 2), blk, 0, stream>>>(ZCU, ZCU, Wt1Ph, Wt1Pl,
                ZF, ZU, ZU, Ub, ZCF, ZCU, ZCU, 1, ZCF, ZCF, ZU, ZU, ZF,
                KQh + (long long)v0*DM, KQl + (long long)v0*DM, KCh, KCl,
                IDX + (long long)v0*MCTX, ZF, ZCF, VC * MCTX, DH, DM);
            wsum_k<<<dim3(VC), dim3(512), 0, stream>>>(Ub, PRB + (long long)v0*MCTX,
                                                       UQv + (long long)v0*DH);
        }
    }
    split_k<<<dim3((NB*DH+255)/256), blk, 0, stream>>>(UQv, UQvh, UQvl, (long long)NB*DH);
    mixprep_sp<<<dim3(NB), blk, 0, stream>>>(HQ2h, HQ2l, YB, Wy, by, bt2);
    gemm_d<<<dim3(NB/64, 1), blk, 0, stream>>>(UQvh, UQvl, Wt2Ph, Wt2Pl,
        ZF, XQh, XQl, ZU, ZCF, HQ2h, HQ2l, 0, ZCF, ZCF, ZU, ZU, ZF,
        ZCU, ZCU, ZCU, ZCU, ZI, ZF, ZCF, NB, DM, DH);

    /* ---- predictor block + head ---- */
    gemm_d<<<dim3(NB/64, 2), blk, 0, stream>>>(XQh, XQl, Wp1Ph, Wp1Pl,
        ZF, TQh, TQl, ZU, bp1, ZCU, ZCU, 1, ZCF, ZCF, ZU, ZU, ZF,
        ZCU, ZCU, ZCU, ZCU, ZI, ZF, ZCF, NB, DH, DM);
    gemm_d<<<dim3(NB/64, 1), blk, 0, stream>>>(TQh, TQl, Wp2Ph, Wp2Pl,
        XQ2f, ZU, ZU, ZU, bp2, XQh, XQl, 0, ZCF, ZCF, ZU, ZU, ZF,
        ZCU, ZCU, ZCU, ZCU, ZI, ZF, ZCF, NB, DM, DH);
    head_k<<<dim3(NB), blk, 0, stream>>>(XQ2f, g_h, b_h, Wh, bh, out);
}